// Round 3
// baseline (394.730 us; speedup 1.0000x reference)
//
#include <hip/hip_runtime.h>
#include <stdint.h>

typedef __bf16 bf16;
typedef __bf16 bf16x4 __attribute__((ext_vector_type(4)));
typedef __bf16 bf16x8 __attribute__((ext_vector_type(8)));
typedef float  f32x4  __attribute__((ext_vector_type(4)));

#define DIM   768
#define HEADS 12
#define HD    64
#define SEQ   4096
#define NKT   24   // 768 / BK32

// ---- async global->LDS, 16B per lane ----
__device__ __forceinline__ void gload16(const void* g, void* l) {
  typedef const __attribute__((address_space(1))) uint32_t* gp_t;
  typedef __attribute__((address_space(3))) uint32_t* lp_t;
  gp_t gp = reinterpret_cast<gp_t>(reinterpret_cast<uintptr_t>(g));
  lp_t lp = reinterpret_cast<lp_t>(reinterpret_cast<uintptr_t>(l));
  __builtin_amdgcn_global_load_lds(gp, lp, 16, 0, 0);
}

// ---- weight fp32 -> bf16 convert ----
__global__ __launch_bounds__(256) void wcvt_kernel(const float* __restrict__ src,
                                                   bf16* __restrict__ dst) {
  int i = (blockIdx.x * 256 + threadIdx.x) * 4;
  float4 v = *reinterpret_cast<const float4*>(src + i);
  bf16x4 o;
  o[0] = (bf16)v.x; o[1] = (bf16)v.y; o[2] = (bf16)v.z; o[3] = (bf16)v.w;
  *reinterpret_cast<bf16x4*>(dst + i) = o;
}

// ---- LayerNorm: one wave per row, fp32 stats, bf16 out ----
__global__ __launch_bounds__(256) void ln_kernel(const float* __restrict__ x,
    const float* __restrict__ gam, const float* __restrict__ bet,
    bf16* __restrict__ y) {
  const int tid = threadIdx.x, w = tid >> 6, l = tid & 63;
  const int row = blockIdx.x * 4 + w;
  const float* xr = x + (long)row * DIM;
  float4 v[3];
  float s = 0.f, ss = 0.f;
#pragma unroll
  for (int j = 0; j < 3; j++) {
    v[j] = *reinterpret_cast<const float4*>(xr + l * 4 + j * 256);
    s  += v[j].x + v[j].y + v[j].z + v[j].w;
    ss += v[j].x * v[j].x + v[j].y * v[j].y + v[j].z * v[j].z + v[j].w * v[j].w;
  }
#pragma unroll
  for (int m = 1; m < 64; m <<= 1) { s += __shfl_xor(s, m); ss += __shfl_xor(ss, m); }
  const float mu = s * (1.f / 768.f);
  const float rstd = rsqrtf(ss * (1.f / 768.f) - mu * mu + 1e-5f);
  bf16* yr = y + (long)row * DIM;
#pragma unroll
  for (int j = 0; j < 3; j++) {
    int c = l * 4 + j * 256;
    float4 g4 = *reinterpret_cast<const float4*>(gam + c);
    float4 b4 = *reinterpret_cast<const float4*>(bet + c);
    bf16x4 o;
    o[0] = (bf16)((v[j].x - mu) * rstd * g4.x + b4.x);
    o[1] = (bf16)((v[j].y - mu) * rstd * g4.y + b4.y);
    o[2] = (bf16)((v[j].z - mu) * rstd * g4.z + b4.z);
    o[3] = (bf16)((v[j].w - mu) * rstd * g4.w + b4.w);
    *reinterpret_cast<bf16x4*>(yr + c) = o;
  }
}

// ---- 256x256 bf16 MFMA GEMM, C = A[M,768] * Bw[N,768]^T ----
// Deep pipeline: BK=32, ring-4 LDS (128KB), counted vmcnt(12), T2 swizzle, T5.
// MODE 0: qkv (elu+1 on q,k; scatter per-head), NT=9
// MODE 1: proj (+bias, fp32 out [t][768]), NT=3
template <int MODE>
__global__ __launch_bounds__(512, 2) void gemm_kernel(
    const bf16* __restrict__ A, const bf16* __restrict__ Bw,
    bf16* __restrict__ qb, bf16* __restrict__ kb, bf16* __restrict__ vb,
    float* __restrict__ outp, const float* __restrict__ bias) {
  // ring of 4 slots x 32KB: [A 256x32][B 256x32] bf16 each
  __shared__ __align__(16) char lds[131072];
  const int tid = threadIdx.x;
  const int wid = tid >> 6, l = tid & 63;
  const int wr = wid >> 2, wc = wid & 3;      // 2 x 4 wave grid
  const int l16 = l & 15, l4 = l >> 4;

  const int NT = (MODE == 0) ? 9 : 3;
  const int nwg = NT * 128;                    // M-tiles = 128
  const int orig = blockIdx.x;
  const int wgid = (orig & 7) * (nwg >> 3) + (orig >> 3);  // T1 bijective
  const int mt = wgid / NT, nt = wgid % NT;

  // stage tile t: linear LDS dest, inverse-swizzled global source (rule #21)
  auto STAGE = [&](int t) {
    const int slot = (t & 3) * 32768;
    const int k0 = t * 32;
#pragma unroll
    for (int g = 0; g < 2; g++) {
      int L = g * 8192 + tid * 16;
      int r = L >> 6;                               // row (64B rows)
      int cb = (L & 63) ^ (((L >> 7) & 3) << 4);    // swizzled byte col
      int ce = cb >> 1;                             // element col
      gload16(A + (long)(mt * 256 + r) * DIM + k0 + ce, lds + slot + L);
      gload16(Bw + (long)(nt * 256 + r) * DIM + k0 + ce, lds + slot + 16384 + L);
    }
  };

  f32x4 acc[8][4];
#pragma unroll
  for (int m = 0; m < 8; m++)
#pragma unroll
    for (int n = 0; n < 4; n++) { f32x4 z4 = {0.f, 0.f, 0.f, 0.f}; acc[m][n] = z4; }

  STAGE(0); STAGE(1); STAGE(2);

  for (int t = 0; t < NKT; t++) {
    __syncthreads();                 // all reads of tile t-1 complete
    if (t + 3 < NKT) STAGE(t + 3);   // overwrites slot (t-1)&3 -- safe
    const int ahead = NKT - 1 - t;
    if (ahead >= 3)      asm volatile("s_waitcnt vmcnt(12)" ::: "memory");
    else if (ahead == 2) asm volatile("s_waitcnt vmcnt(8)" ::: "memory");
    else if (ahead == 1) asm volatile("s_waitcnt vmcnt(4)" ::: "memory");
    else                 asm volatile("s_waitcnt vmcnt(0)" ::: "memory");
    __syncthreads();                 // tile t visible to all waves

    const int slot = (t & 3) * 32768;
    bf16x8 a[8], b[4];
#pragma unroll
    for (int mi = 0; mi < 8; mi++) {
      int off = (wr * 128 + mi * 16 + l16) * 64 + l4 * 16;
      off ^= ((off >> 7) & 3) << 4;
      a[mi] = *reinterpret_cast<const bf16x8*>(lds + slot + off);
    }
#pragma unroll
    for (int ni = 0; ni < 4; ni++) {
      int off = (wc * 64 + ni * 16 + l16) * 64 + l4 * 16;
      off ^= ((off >> 7) & 3) << 4;
      b[ni] = *reinterpret_cast<const bf16x8*>(lds + slot + 16384 + off);
    }
    __builtin_amdgcn_s_setprio(1);
#pragma unroll
    for (int mi = 0; mi < 8; mi++)
#pragma unroll
      for (int ni = 0; ni < 4; ni++)
        acc[mi][ni] = __builtin_amdgcn_mfma_f32_16x16x32_bf16(a[mi], b[ni], acc[mi][ni], 0, 0, 0);
    __builtin_amdgcn_s_setprio(0);
  }

  if constexpr (MODE == 0) {
    // epilogue: reuse ring LDS as Cs[256][128] bf16 (64KB), 2 column passes
    bf16* Cs = (bf16*)lds;
    const int s = nt / 3;   // 0=q,1=k,2=v
    const int j = nt % 3;   // head group base j*4
    bf16* dst0 = (s == 0) ? qb : (s == 1) ? kb : vb;
#pragma unroll
    for (int p = 0; p < 2; p++) {
      __syncthreads();
      if ((wc >> 1) == p) {
#pragma unroll
        for (int mi = 0; mi < 8; mi++)
#pragma unroll
          for (int ni = 0; ni < 4; ni++)
#pragma unroll
            for (int i = 0; i < 4; i++) {
              float val = acc[mi][ni][i];
              if (s < 2) val = val > 0.f ? val + 1.f : __expf(val);
              int row = wr * 128 + mi * 16 + l4 * 4 + i;
              int col = (wc & 1) * 64 + ni * 16 + l16;
              Cs[row * 128 + col] = (bf16)val;
            }
      }
      __syncthreads();
#pragma unroll
      for (int it = 0; it < 8; it++) {
        int bi = it * 8192 + tid * 16;
        int row = bi >> 8;
        int col = (bi & 255) >> 1;
        int hh = 2 * p + (col >> 6), d = col & 63;
        int trow = mt * 256 + row;
        int bb = trow >> 12, tok = trow & 4095;
        *reinterpret_cast<bf16x8*>(dst0 +
            ((long)(bb * HEADS + j * 4 + hh) * SEQ + tok) * HD + d) =
            *reinterpret_cast<const bf16x8*>(Cs + (bi >> 1));
      }
    }
  } else {
#pragma unroll
    for (int ni = 0; ni < 4; ni++) {
      int col = nt * 256 + wc * 64 + ni * 16 + l16;
      float bv = bias[col];
#pragma unroll
      for (int mi = 0; mi < 8; mi++)
#pragma unroll
        for (int i = 0; i < 4; i++) {
          long trow = mt * 256 + wr * 128 + mi * 16 + l4 * 4 + i;
          outp[trow * DIM + col] = acc[mi][ni][i] + bv;
        }
    }
  }
}

// ---- kv partials: per (head, split of 512 tokens): kv[64][64] += k^T v ; ksum ----
__global__ __launch_bounds__(256) void kv_kernel(
    const bf16* __restrict__ kb, const bf16* __restrict__ vb,
    float* __restrict__ kv_part, float* __restrict__ ks_part) {
  __shared__ __align__(16) union UU {
    struct { bf16 Ks[128 * 64]; bf16 Vs[128 * 64]; } s;
    float red[8192];
  } u;
  __shared__ float ksred[4][64];
  const int head = blockIdx.x, sp = blockIdx.y;
  const int tid = threadIdx.x, w = tid >> 6, l = tid & 63;
  const int d0 = (l >> 3) * 8, e0 = (l & 7) * 8;
  const bf16* K = kb + (long)(head * SEQ + sp * 512) * HD;
  const bf16* V = vb + (long)(head * SEQ + sp * 512) * HD;
  float acc[8][8];
#pragma unroll
  for (int i = 0; i < 8; i++)
#pragma unroll
    for (int jj = 0; jj < 8; jj++) acc[i][jj] = 0.f;
  float ks[8] = {0.f, 0.f, 0.f, 0.f, 0.f, 0.f, 0.f, 0.f};

  for (int t0 = 0; t0 < 512; t0 += 128) {
    __syncthreads();
#pragma unroll
    for (int r = 0; r < 4; r++) {
      gload16(K + t0 * 64 + r * 2048 + tid * 8, u.s.Ks + r * 2048 + tid * 8);
      gload16(V + t0 * 64 + r * 2048 + tid * 8, u.s.Vs + r * 2048 + tid * 8);
    }
    __syncthreads();
    for (int n = w * 32; n < w * 32 + 32; n++) {
      bf16x8 k8 = *reinterpret_cast<const bf16x8*>(u.s.Ks + n * 64 + d0);
      bf16x8 v8 = *reinterpret_cast<const bf16x8*>(u.s.Vs + n * 64 + e0);
      float kf[8], vf[8];
#pragma unroll
      for (int i = 0; i < 8; i++) { kf[i] = (float)k8[i]; vf[i] = (float)v8[i]; }
#pragma unroll
      for (int i = 0; i < 8; i++) {
        ks[i] += kf[i];
#pragma unroll
        for (int jj = 0; jj < 8; jj++) acc[i][jj] += kf[i] * vf[jj];
      }
    }
  }
  if ((l & 7) == 0) {
#pragma unroll
    for (int i = 0; i < 8; i++) ksred[w][d0 + i] = ks[i];
  }
  __syncthreads();
  if (w >= 2) {
    float* dst = u.red + (w - 2) * 4096;
#pragma unroll
    for (int i = 0; i < 8; i++) {
      f32x4 a = {acc[i][0], acc[i][1], acc[i][2], acc[i][3]};
      f32x4 b = {acc[i][4], acc[i][5], acc[i][6], acc[i][7]};
      *reinterpret_cast<f32x4*>(dst + (d0 + i) * 64 + e0) = a;
      *reinterpret_cast<f32x4*>(dst + (d0 + i) * 64 + e0 + 4) = b;
    }
  }
  __syncthreads();
  if (w < 2) {
    const float* src = u.red + w * 4096;
#pragma unroll
    for (int i = 0; i < 8; i++)
#pragma unroll
      for (int jj = 0; jj < 8; jj++) acc[i][jj] += src[(d0 + i) * 64 + e0 + jj];
  }
  __syncthreads();
  if (w == 1) {
    float* dst = u.red;
#pragma unroll
    for (int i = 0; i < 8; i++) {
      f32x4 a = {acc[i][0], acc[i][1], acc[i][2], acc[i][3]};
      f32x4 b = {acc[i][4], acc[i][5], acc[i][6], acc[i][7]};
      *reinterpret_cast<f32x4*>(dst + (d0 + i) * 64 + e0) = a;
      *reinterpret_cast<f32x4*>(dst + (d0 + i) * 64 + e0 + 4) = b;
    }
  }
  __syncthreads();
  if (w == 0) {
    const float* src = u.red;
#pragma unroll
    for (int i = 0; i < 8; i++)
#pragma unroll
      for (int jj = 0; jj < 8; jj++) acc[i][jj] += src[(d0 + i) * 64 + e0 + jj];
    float* dst = kv_part + (long)(head * 8 + sp) * 4096;
#pragma unroll
    for (int i = 0; i < 8; i++) {
      f32x4 a = {acc[i][0], acc[i][1], acc[i][2], acc[i][3]};
      f32x4 b = {acc[i][4], acc[i][5], acc[i][6], acc[i][7]};
      *reinterpret_cast<f32x4*>(dst + (d0 + i) * 64 + e0) = a;
      *reinterpret_cast<f32x4*>(dst + (d0 + i) * 64 + e0 + 4) = b;
    }
  }
  if (tid < 64)
    ks_part[(head * 8 + sp) * 64 + tid] =
        ksred[0][tid] + ksred[1][tid] + ksred[2][tid] + ksred[3][tid];
}

// ---- finalize: sum partials -> kvT bf16 [head][e][d], ksum fp32 [head][d] ----
__global__ __launch_bounds__(256) void kvfin_kernel(const float* __restrict__ kv_part,
    const float* __restrict__ ks_part, bf16* __restrict__ kvT, float* __restrict__ ksum) {
  const int head = blockIdx.x, tid = threadIdx.x;
  const long base = (long)head * 8 * 4096;
  const int d = tid >> 2, ecol = (tid & 3) * 16;
  float s[16];
#pragma unroll
  for (int q = 0; q < 16; q++) s[q] = 0.f;
  for (int sp = 0; sp < 8; sp++) {
    const float* p = kv_part + base + sp * 4096 + d * 64 + ecol;
#pragma unroll
    for (int q = 0; q < 16; q++) s[q] += p[q];
  }
#pragma unroll
  for (int q = 0; q < 16; q++) kvT[head * 4096 + (ecol + q) * 64 + d] = (bf16)s[q];
  if (tid < 64) {
    float t = 0.f;
    for (int sp = 0; sp < 8; sp++) t += ks_part[(head * 8 + sp) * 64 + tid];
    ksum[head * 64 + tid] = t;
  }
}

// ---- out_pre = (Q @ kv) * z, bf16 out in [t][768] layout ----
__global__ __launch_bounds__(256) void qout_kernel(const bf16* __restrict__ qb,
    const bf16* __restrict__ kvT, const float* __restrict__ ksum,
    bf16* __restrict__ outp) {
  __shared__ __align__(16) bf16 Qs[128 * 64];
  __shared__ __align__(16) bf16 Bs2[64 * 64];
  __shared__ float ksum_s[64];
  __shared__ float z_s[128];
  const int head = blockIdx.x, tt = blockIdx.y;
  const int b = head / HEADS, h = head % HEADS;
  const int tid = threadIdx.x, w = tid >> 6, l = tid & 63;
  const int l16 = l & 15, l4 = l >> 4;
  const bf16* Qg = qb + (long)(head * SEQ + tt * 128) * HD;
#pragma unroll
  for (int r = 0; r < 4; r++) gload16(Qg + r * 2048 + tid * 8, Qs + r * 2048 + tid * 8);
#pragma unroll
  for (int r = 0; r < 2; r++)
    gload16(kvT + head * 4096 + r * 2048 + tid * 8, Bs2 + r * 2048 + tid * 8);
  if (tid < 64) ksum_s[tid] = ksum[head * 64 + tid];
  __syncthreads();
  if (tid < 128) {
    float dsum = 0.f;
#pragma unroll
    for (int i = 0; i < 8; i++) {
      bf16x8 q8 = *reinterpret_cast<const bf16x8*>(Qg + tid * 64 + i * 8);
#pragma unroll
      for (int jj = 0; jj < 8; jj++) dsum += (float)q8[jj] * ksum_s[i * 8 + jj];
    }
    z_s[tid] = 1.f / (dsum + 1e-6f);
  }
  f32x4 acc[2][4];
#pragma unroll
  for (int m = 0; m < 2; m++)
#pragma unroll
    for (int n = 0; n < 4; n++) { f32x4 z4 = {0.f, 0.f, 0.f, 0.f}; acc[m][n] = z4; }
#pragma unroll
  for (int kk = 0; kk < 2; kk++) {
    bf16x8 af[2], bfr[4];
#pragma unroll
    for (int m = 0; m < 2; m++)
      af[m] = *reinterpret_cast<const bf16x8*>(Qs + (w * 32 + m * 16 + l16) * 64 + kk * 32 + l4 * 8);
#pragma unroll
    for (int n = 0; n < 4; n++)
      bfr[n] = *reinterpret_cast<const bf16x8*>(Bs2 + (n * 16 + l16) * 64 + kk * 32 + l4 * 8);
#pragma unroll
    for (int m = 0; m < 2; m++)
#pragma unroll
      for (int n = 0; n < 4; n++)
        acc[m][n] = __builtin_amdgcn_mfma_f32_16x16x32_bf16(af[m], bfr[n], acc[m][n], 0, 0, 0);
  }
  __syncthreads();
#pragma unroll
  for (int m = 0; m < 2; m++)
#pragma unroll
    for (int n = 0; n < 4; n++)
#pragma unroll
      for (int i = 0; i < 4; i++) {
        int row = w * 32 + m * 16 + l4 * 4 + i;
        Qs[row * 64 + n * 16 + l16] = (bf16)(acc[m][n][i] * z_s[row]);
      }
  __syncthreads();
#pragma unroll
  for (int r = 0; r < 4; r++) {
    int idx = r * 2048 + tid * 8;
    int row = idx >> 6, col = idx & 63;
    *reinterpret_cast<bf16x8*>(outp + (long)(b * SEQ + tt * 128 + row) * DIM + h * HD + col) =
        *reinterpret_cast<const bf16x8*>(Qs + idx);
  }
}

extern "C" void kernel_launch(void* const* d_in, const int* in_sizes, int n_in,
                              void* d_out, int out_size, void* d_ws, size_t ws_size,
                              hipStream_t stream) {
  const float* x     = (const float*)d_in[0];
  const float* gam   = (const float*)d_in[1];
  const float* bet   = (const float*)d_in[2];
  const float* wqkv  = (const float*)d_in[3];
  const float* wproj = (const float*)d_in[4];
  const float* bproj = (const float*)d_in[5];
  float* out = (float*)d_out;
  char* ws = (char*)d_ws;

  bf16*  y       = (bf16*)(ws);                    // 50331648 B (reused as out_pre)
  bf16*  qb      = (bf16*)(ws + 50331648);         // 50331648 B
  bf16*  kb      = (bf16*)(ws + 100663296);        // 50331648 B
  bf16*  vb      = (bf16*)(ws + 150994944);        // 50331648 B
  bf16*  wqkv_b  = (bf16*)(ws + 201326592);        // 3538944 B
  bf16*  wproj_b = (bf16*)(ws + 204865536);        // 1179648 B
  float* kv_part = (float*)(ws + 206045184);       // 12582912 B
  float* ks_part = (float*)(ws + 218628096);       // 196608 B
  bf16*  kvT     = (bf16*)(ws + 218824704);        // 786432 B
  float* ksum    = (float*)(ws + 219611136);       // 24576 B

  wcvt_kernel<<<1728, 256, 0, stream>>>(wqkv, wqkv_b);
  wcvt_kernel<<<576, 256, 0, stream>>>(wproj, wproj_b);
  ln_kernel<<<8192, 256, 0, stream>>>(x, gam, bet, y);
  gemm_kernel<0><<<dim3(9 * 128), 512, 0, stream>>>(y, wqkv_b, qb, kb, vb, nullptr, nullptr);
  kv_kernel<<<dim3(96, 8), 256, 0, stream>>>(kb, vb, kv_part, ks_part);
  kvfin_kernel<<<96, 256, 0, stream>>>(kv_part, ks_part, kvT, ksum);
  qout_kernel<<<dim3(96, 32), 256, 0, stream>>>(qb, kvT, ksum, y);
  gemm_kernel<1><<<dim3(3 * 128), 512, 0, stream>>>(y, wproj_b, nullptr, nullptr, nullptr, out, bproj);
}

// Round 4
// 343.382 us; speedup vs baseline: 1.1495x; 1.1495x over previous
//
#include <hip/hip_runtime.h>
#include <stdint.h>

typedef __bf16 bf16;
typedef __bf16 bf16x4 __attribute__((ext_vector_type(4)));
typedef __bf16 bf16x8 __attribute__((ext_vector_type(8)));
typedef float  f32x4  __attribute__((ext_vector_type(4)));

#define DIM   768
#define HEADS 12
#define HD    64
#define SEQ   4096
#define NKT   24   // 768 / BK32

// ---- async global->LDS, 16B per lane ----
__device__ __forceinline__ void gload16(const void* g, void* l) {
  typedef const __attribute__((address_space(1))) uint32_t* gp_t;
  typedef __attribute__((address_space(3))) uint32_t* lp_t;
  gp_t gp = reinterpret_cast<gp_t>(reinterpret_cast<uintptr_t>(g));
  lp_t lp = reinterpret_cast<lp_t>(reinterpret_cast<uintptr_t>(l));
  __builtin_amdgcn_global_load_lds(gp, lp, 16, 0, 0);
}

// ---- weight fp32 -> bf16 convert ----
__global__ __launch_bounds__(256) void wcvt_kernel(const float* __restrict__ src,
                                                   bf16* __restrict__ dst) {
  int i = (blockIdx.x * 256 + threadIdx.x) * 4;
  float4 v = *reinterpret_cast<const float4*>(src + i);
  bf16x4 o;
  o[0] = (bf16)v.x; o[1] = (bf16)v.y; o[2] = (bf16)v.z; o[3] = (bf16)v.w;
  *reinterpret_cast<bf16x4*>(dst + i) = o;
}

// ---- LayerNorm: one wave per row, fp32 stats, bf16 out ----
__global__ __launch_bounds__(256) void ln_kernel(const float* __restrict__ x,
    const float* __restrict__ gam, const float* __restrict__ bet,
    bf16* __restrict__ y) {
  const int tid = threadIdx.x, w = tid >> 6, l = tid & 63;
  const int row = blockIdx.x * 4 + w;
  const float* xr = x + (long)row * DIM;
  float4 v[3];
  float s = 0.f, ss = 0.f;
#pragma unroll
  for (int j = 0; j < 3; j++) {
    v[j] = *reinterpret_cast<const float4*>(xr + l * 4 + j * 256);
    s  += v[j].x + v[j].y + v[j].z + v[j].w;
    ss += v[j].x * v[j].x + v[j].y * v[j].y + v[j].z * v[j].z + v[j].w * v[j].w;
  }
#pragma unroll
  for (int m = 1; m < 64; m <<= 1) { s += __shfl_xor(s, m); ss += __shfl_xor(ss, m); }
  const float mu = s * (1.f / 768.f);
  const float rstd = rsqrtf(ss * (1.f / 768.f) - mu * mu + 1e-5f);
  bf16* yr = y + (long)row * DIM;
#pragma unroll
  for (int j = 0; j < 3; j++) {
    int c = l * 4 + j * 256;
    float4 g4 = *reinterpret_cast<const float4*>(gam + c);
    float4 b4 = *reinterpret_cast<const float4*>(bet + c);
    bf16x4 o;
    o[0] = (bf16)((v[j].x - mu) * rstd * g4.x + b4.x);
    o[1] = (bf16)((v[j].y - mu) * rstd * g4.y + b4.y);
    o[2] = (bf16)((v[j].z - mu) * rstd * g4.z + b4.z);
    o[3] = (bf16)((v[j].w - mu) * rstd * g4.w + b4.w);
    *reinterpret_cast<bf16x4*>(yr + c) = o;
  }
}

// ---- 256x256 bf16 MFMA GEMM, C = A[M,768] * Bw[N,768]^T ----
// Deep pipeline: BK=32, ring-4 LDS, counted vmcnt (T4), RAW s_barrier (no
// implicit vmcnt(0) drain -- the round-3 bug), T2 swizzle, T5 setprio.
// MODE 0: qkv (elu+1 on q,k; scatter per-head), NT=9
// MODE 1: proj (+bias, fp32 out [t][768]), NT=3
template <int MODE>
__global__ __launch_bounds__(512, 2) void gemm_kernel(
    const bf16* __restrict__ A, const bf16* __restrict__ Bw,
    bf16* __restrict__ qb, bf16* __restrict__ kb, bf16* __restrict__ vb,
    float* __restrict__ outp, const float* __restrict__ bias) {
  // ring of 4 slots x 32KB: [A 256x32][B 256x32] bf16 each
  __shared__ __align__(16) char lds[131072];
  const int tid = threadIdx.x;
  const int wid = tid >> 6, l = tid & 63;
  const int wr = wid >> 2, wc = wid & 3;      // 2 x 4 wave grid
  const int l16 = l & 15, l4 = l >> 4;

  const int NT = (MODE == 0) ? 9 : 3;
  const int nwg = NT * 128;                    // M-tiles = 128
  const int orig = blockIdx.x;
  const int wgid = (orig & 7) * (nwg >> 3) + (orig >> 3);  // T1 bijective
  const int mt = wgid / NT, nt = wgid % NT;

  // stage tile t: linear LDS dest, inverse-swizzled global source (rule #21)
  auto STAGE = [&](int t) {
    const int slot = (t & 3) * 32768;
    const int k0 = t * 32;
#pragma unroll
    for (int g = 0; g < 2; g++) {
      int L = g * 8192 + tid * 16;
      int r = L >> 6;                               // row (64B rows)
      int cb = (L & 63) ^ (((L >> 7) & 3) << 4);    // swizzled byte col
      int ce = cb >> 1;                             // element col
      gload16(A + (long)(mt * 256 + r) * DIM + k0 + ce, lds + slot + L);
      gload16(Bw + (long)(nt * 256 + r) * DIM + k0 + ce, lds + slot + 16384 + L);
    }
  };

  f32x4 acc[8][4];
#pragma unroll
  for (int m = 0; m < 8; m++)
#pragma unroll
    for (int n = 0; n < 4; n++) { f32x4 z4 = {0.f, 0.f, 0.f, 0.f}; acc[m][n] = z4; }

  STAGE(0); STAGE(1); STAGE(2);

  for (int t = 0; t < NKT; t++) {
    // barrier A: all waves done READING slot (t-1)&3 (their ds_reads were
    // drained by lgkmcnt before the MFMAs that consumed them). Raw barrier:
    // no vmcnt drain, prefetches stay in flight.
    __builtin_amdgcn_s_barrier();
    if (t + 3 < NKT) STAGE(t + 3);   // overwrites slot (t-1)&3 -- safe
    const int ahead = NKT - 1 - t;
    if (ahead >= 3)      asm volatile("s_waitcnt vmcnt(12)" ::: "memory");
    else if (ahead == 2) asm volatile("s_waitcnt vmcnt(8)" ::: "memory");
    else if (ahead == 1) asm volatile("s_waitcnt vmcnt(4)" ::: "memory");
    else                 asm volatile("s_waitcnt vmcnt(0)" ::: "memory");
    // barrier B: every wave has passed its counted wait -> tile t's DMA
    // writes (from ALL waves) have landed in LDS.
    __builtin_amdgcn_s_barrier();
    asm volatile("" ::: "memory");          // no LDS-read hoist above barrier
    __builtin_amdgcn_sched_barrier(0);

    const int slot = (t & 3) * 32768;
    bf16x8 a[8], b[4];
#pragma unroll
    for (int mi = 0; mi < 8; mi++) {
      int off = (wr * 128 + mi * 16 + l16) * 64 + l4 * 16;
      off ^= ((off >> 7) & 3) << 4;
      a[mi] = *reinterpret_cast<const bf16x8*>(lds + slot + off);
    }
#pragma unroll
    for (int ni = 0; ni < 4; ni++) {
      int off = (wc * 64 + ni * 16 + l16) * 64 + l4 * 16;
      off ^= ((off >> 7) & 3) << 4;
      b[ni] = *reinterpret_cast<const bf16x8*>(lds + slot + 16384 + off);
    }
    __builtin_amdgcn_s_setprio(1);
#pragma unroll
    for (int mi = 0; mi < 8; mi++)
#pragma unroll
      for (int ni = 0; ni < 4; ni++)
        acc[mi][ni] = __builtin_amdgcn_mfma_f32_16x16x32_bf16(a[mi], b[ni], acc[mi][ni], 0, 0, 0);
    __builtin_amdgcn_s_setprio(0);
  }
  // last iteration waited vmcnt(0): no DMA in flight; epilogue barriers drain lgkm.

  if constexpr (MODE == 0) {
    // epilogue: reuse ring LDS as Cs[256][128] bf16 (64KB), 2 column passes
    bf16* Cs = (bf16*)lds;
    const int s = nt / 3;   // 0=q,1=k,2=v
    const int j = nt % 3;   // head group base j*4
    bf16* dst0 = (s == 0) ? qb : (s == 1) ? kb : vb;
#pragma unroll
    for (int p = 0; p < 2; p++) {
      __syncthreads();
      if ((wc >> 1) == p) {
#pragma unroll
        for (int mi = 0; mi < 8; mi++)
#pragma unroll
          for (int ni = 0; ni < 4; ni++)
#pragma unroll
            for (int i = 0; i < 4; i++) {
              float val = acc[mi][ni][i];
              if (s < 2) val = val > 0.f ? val + 1.f : __expf(val);
              int row = wr * 128 + mi * 16 + l4 * 4 + i;
              int col = (wc & 1) * 64 + ni * 16 + l16;
              Cs[row * 128 + col] = (bf16)val;
            }
      }
      __syncthreads();
#pragma unroll
      for (int it = 0; it < 8; it++) {
        int bi = it * 8192 + tid * 16;
        int row = bi >> 8;
        int col = (bi & 255) >> 1;
        int hh = 2 * p + (col >> 6), d = col & 63;
        int trow = mt * 256 + row;
        int bb = trow >> 12, tok = trow & 4095;
        *reinterpret_cast<bf16x8*>(dst0 +
            ((long)(bb * HEADS + j * 4 + hh) * SEQ + tok) * HD + d) =
            *reinterpret_cast<const bf16x8*>(Cs + (bi >> 1));
      }
    }
  } else {
#pragma unroll
    for (int ni = 0; ni < 4; ni++) {
      int col = nt * 256 + wc * 64 + ni * 16 + l16;
      float bv = bias[col];
#pragma unroll
      for (int mi = 0; mi < 8; mi++)
#pragma unroll
        for (int i = 0; i < 4; i++) {
          long trow = mt * 256 + wr * 128 + mi * 16 + l4 * 4 + i;
          outp[trow * DIM + col] = acc[mi][ni][i] + bv;
        }
    }
  }
}

// ---- kv partials: per (head, split of 512 tokens): kv[64][64] += k^T v ; ksum ----
__global__ __launch_bounds__(256) void kv_kernel(
    const bf16* __restrict__ kb, const bf16* __restrict__ vb,
    float* __restrict__ kv_part, float* __restrict__ ks_part) {
  __shared__ __align__(16) union UU {
    struct { bf16 Ks[128 * 64]; bf16 Vs[128 * 64]; } s;
    float red[8192];
  } u;
  __shared__ float ksred[4][64];
  const int head = blockIdx.x, sp = blockIdx.y;
  const int tid = threadIdx.x, w = tid >> 6, l = tid & 63;
  const int d0 = (l >> 3) * 8, e0 = (l & 7) * 8;
  const bf16* K = kb + (long)(head * SEQ + sp * 512) * HD;
  const bf16* V = vb + (long)(head * SEQ + sp * 512) * HD;
  float acc[8][8];
#pragma unroll
  for (int i = 0; i < 8; i++)
#pragma unroll
    for (int jj = 0; jj < 8; jj++) acc[i][jj] = 0.f;
  float ks[8] = {0.f, 0.f, 0.f, 0.f, 0.f, 0.f, 0.f, 0.f};

  for (int t0 = 0; t0 < 512; t0 += 128) {
    __syncthreads();
#pragma unroll
    for (int r = 0; r < 4; r++) {
      gload16(K + t0 * 64 + r * 2048 + tid * 8, u.s.Ks + r * 2048 + tid * 8);
      gload16(V + t0 * 64 + r * 2048 + tid * 8, u.s.Vs + r * 2048 + tid * 8);
    }
    __syncthreads();
    for (int n = w * 32; n < w * 32 + 32; n++) {
      bf16x8 k8 = *reinterpret_cast<const bf16x8*>(u.s.Ks + n * 64 + d0);
      bf16x8 v8 = *reinterpret_cast<const bf16x8*>(u.s.Vs + n * 64 + e0);
      float kf[8], vf[8];
#pragma unroll
      for (int i = 0; i < 8; i++) { kf[i] = (float)k8[i]; vf[i] = (float)v8[i]; }
#pragma unroll
      for (int i = 0; i < 8; i++) {
        ks[i] += kf[i];
#pragma unroll
        for (int jj = 0; jj < 8; jj++) acc[i][jj] += kf[i] * vf[jj];
      }
    }
  }
  if ((l & 7) == 0) {
#pragma unroll
    for (int i = 0; i < 8; i++) ksred[w][d0 + i] = ks[i];
  }
  __syncthreads();
  if (w >= 2) {
    float* dst = u.red + (w - 2) * 4096;
#pragma unroll
    for (int i = 0; i < 8; i++) {
      f32x4 a = {acc[i][0], acc[i][1], acc[i][2], acc[i][3]};
      f32x4 b = {acc[i][4], acc[i][5], acc[i][6], acc[i][7]};
      *reinterpret_cast<f32x4*>(dst + (d0 + i) * 64 + e0) = a;
      *reinterpret_cast<f32x4*>(dst + (d0 + i) * 64 + e0 + 4) = b;
    }
  }
  __syncthreads();
  if (w < 2) {
    const float* src = u.red + w * 4096;
#pragma unroll
    for (int i = 0; i < 8; i++)
#pragma unroll
      for (int jj = 0; jj < 8; jj++) acc[i][jj] += src[(d0 + i) * 64 + e0 + jj];
  }
  __syncthreads();
  if (w == 1) {
    float* dst = u.red;
#pragma unroll
    for (int i = 0; i < 8; i++) {
      f32x4 a = {acc[i][0], acc[i][1], acc[i][2], acc[i][3]};
      f32x4 b = {acc[i][4], acc[i][5], acc[i][6], acc[i][7]};
      *reinterpret_cast<f32x4*>(dst + (d0 + i) * 64 + e0) = a;
      *reinterpret_cast<f32x4*>(dst + (d0 + i) * 64 + e0 + 4) = b;
    }
  }
  __syncthreads();
  if (w == 0) {
    const float* src = u.red;
#pragma unroll
    for (int i = 0; i < 8; i++)
#pragma unroll
      for (int jj = 0; jj < 8; jj++) acc[i][jj] += src[(d0 + i) * 64 + e0 + jj];
    float* dst = kv_part + (long)(head * 8 + sp) * 4096;
#pragma unroll
    for (int i = 0; i < 8; i++) {
      f32x4 a = {acc[i][0], acc[i][1], acc[i][2], acc[i][3]};
      f32x4 b = {acc[i][4], acc[i][5], acc[i][6], acc[i][7]};
      *reinterpret_cast<f32x4*>(dst + (d0 + i) * 64 + e0) = a;
      *reinterpret_cast<f32x4*>(dst + (d0 + i) * 64 + e0 + 4) = b;
    }
  }
  if (tid < 64)
    ks_part[(head * 8 + sp) * 64 + tid] =
        ksred[0][tid] + ksred[1][tid] + ksred[2][tid] + ksred[3][tid];
}

// ---- finalize: sum partials -> kvT bf16 [head][e][d], ksum fp32 [head][d] ----
__global__ __launch_bounds__(256) void kvfin_kernel(const float* __restrict__ kv_part,
    const float* __restrict__ ks_part, bf16* __restrict__ kvT, float* __restrict__ ksum) {
  const int head = blockIdx.x, tid = threadIdx.x;
  const long base = (long)head * 8 * 4096;
  const int d = tid >> 2, ecol = (tid & 3) * 16;
  float s[16];
#pragma unroll
  for (int q = 0; q < 16; q++) s[q] = 0.f;
  for (int sp = 0; sp < 8; sp++) {
    const float* p = kv_part + base + sp * 4096 + d * 64 + ecol;
#pragma unroll
    for (int q = 0; q < 16; q++) s[q] += p[q];
  }
#pragma unroll
  for (int q = 0; q < 16; q++) kvT[head * 4096 + (ecol + q) * 64 + d] = (bf16)s[q];
  if (tid < 64) {
    float t = 0.f;
    for (int sp = 0; sp < 8; sp++) t += ks_part[(head * 8 + sp) * 64 + tid];
    ksum[head * 64 + tid] = t;
  }
}

// ---- out_pre = (Q @ kv) * z, bf16 out in [t][768] layout ----
__global__ __launch_bounds__(256) void qout_kernel(const bf16* __restrict__ qb,
    const bf16* __restrict__ kvT, const float* __restrict__ ksum,
    bf16* __restrict__ outp) {
  __shared__ __align__(16) bf16 Qs[128 * 64];
  __shared__ __align__(16) bf16 Bs2[64 * 64];
  __shared__ float ksum_s[64];
  __shared__ float z_s[128];
  const int head = blockIdx.x, tt = blockIdx.y;
  const int b = head / HEADS, h = head % HEADS;
  const int tid = threadIdx.x, w = tid >> 6, l = tid & 63;
  const int l16 = l & 15, l4 = l >> 4;
  const bf16* Qg = qb + (long)(head * SEQ + tt * 128) * HD;
#pragma unroll
  for (int r = 0; r < 4; r++) gload16(Qg + r * 2048 + tid * 8, Qs + r * 2048 + tid * 8);
#pragma unroll
  for (int r = 0; r < 2; r++)
    gload16(kvT + head * 4096 + r * 2048 + tid * 8, Bs2 + r * 2048 + tid * 8);
  if (tid < 64) ksum_s[tid] = ksum[head * 64 + tid];
  __syncthreads();
  if (tid < 128) {
    float dsum = 0.f;
#pragma unroll
    for (int i = 0; i < 8; i++) {
      bf16x8 q8 = *reinterpret_cast<const bf16x8*>(Qg + tid * 64 + i * 8);
#pragma unroll
      for (int jj = 0; jj < 8; jj++) dsum += (float)q8[jj] * ksum_s[i * 8 + jj];
    }
    z_s[tid] = 1.f / (dsum + 1e-6f);
  }
  f32x4 acc[2][4];
#pragma unroll
  for (int m = 0; m < 2; m++)
#pragma unroll
    for (int n = 0; n < 4; n++) { f32x4 z4 = {0.f, 0.f, 0.f, 0.f}; acc[m][n] = z4; }
#pragma unroll
  for (int kk = 0; kk < 2; kk++) {
    bf16x8 af[2], bfr[4];
#pragma unroll
    for (int m = 0; m < 2; m++)
      af[m] = *reinterpret_cast<const bf16x8*>(Qs + (w * 32 + m * 16 + l16) * 64 + kk * 32 + l4 * 8);
#pragma unroll
    for (int n = 0; n < 4; n++)
      bfr[n] = *reinterpret_cast<const bf16x8*>(Bs2 + (n * 16 + l16) * 64 + kk * 32 + l4 * 8);
#pragma unroll
    for (int m = 0; m < 2; m++)
#pragma unroll
      for (int n = 0; n < 4; n++)
        acc[m][n] = __builtin_amdgcn_mfma_f32_16x16x32_bf16(af[m], bfr[n], acc[m][n], 0, 0, 0);
  }
  __syncthreads();
#pragma unroll
  for (int m = 0; m < 2; m++)
#pragma unroll
    for (int n = 0; n < 4; n++)
#pragma unroll
      for (int i = 0; i < 4; i++) {
        int row = w * 32 + m * 16 + l4 * 4 + i;
        Qs[row * 64 + n * 16 + l16] = (bf16)(acc[m][n][i] * z_s[row]);
      }
  __syncthreads();
#pragma unroll
  for (int r = 0; r < 4; r++) {
    int idx = r * 2048 + tid * 8;
    int row = idx >> 6, col = idx & 63;
    *reinterpret_cast<bf16x8*>(outp + (long)(b * SEQ + tt * 128 + row) * DIM + h * HD + col) =
        *reinterpret_cast<const bf16x8*>(Qs + idx);
  }
}

extern "C" void kernel_launch(void* const* d_in, const int* in_sizes, int n_in,
                              void* d_out, int out_size, void* d_ws, size_t ws_size,
                              hipStream_t stream) {
  const float* x     = (const float*)d_in[0];
  const float* gam   = (const float*)d_in[1];
  const float* bet   = (const float*)d_in[2];
  const float* wqkv  = (const float*)d_in[3];
  const float* wproj = (const float*)d_in[4];
  const float* bproj = (const float*)d_in[5];
  float* out = (float*)d_out;
  char* ws = (char*)d_ws;

  bf16*  y       = (bf16*)(ws);                    // 50331648 B (reused as out_pre)
  bf16*  qb      = (bf16*)(ws + 50331648);         // 50331648 B
  bf16*  kb      = (bf16*)(ws + 100663296);        // 50331648 B
  bf16*  vb      = (bf16*)(ws + 150994944);        // 50331648 B
  bf16*  wqkv_b  = (bf16*)(ws + 201326592);        // 3538944 B
  bf16*  wproj_b = (bf16*)(ws + 204865536);        // 1179648 B
  float* kv_part = (float*)(ws + 206045184);       // 12582912 B
  float* ks_part = (float*)(ws + 218628096);       // 196608 B
  bf16*  kvT     = (bf16*)(ws + 218824704);        // 786432 B
  float* ksum    = (float*)(ws + 219611136);       // 24576 B

  wcvt_kernel<<<1728, 256, 0, stream>>>(wqkv, wqkv_b);
  wcvt_kernel<<<576, 256, 0, stream>>>(wproj, wproj_b);
  ln_kernel<<<8192, 256, 0, stream>>>(x, gam, bet, y);
  gemm_kernel<0><<<dim3(9 * 128), 512, 0, stream>>>(y, wqkv_b, qb, kb, vb, nullptr, nullptr);
  kv_kernel<<<dim3(96, 8), 256, 0, stream>>>(kb, vb, kv_part, ks_part);
  kvfin_kernel<<<96, 256, 0, stream>>>(kv_part, ks_part, kvT, ksum);
  qout_kernel<<<dim3(96, 32), 256, 0, stream>>>(qb, kvT, ksum, y);
  gemm_kernel<1><<<dim3(3 * 128), 512, 0, stream>>>(y, wproj_b, nullptr, nullptr, nullptr, out, bproj);
}

// Round 5
// 339.382 us; speedup vs baseline: 1.1631x; 1.0118x over previous
//
#include <hip/hip_runtime.h>
#include <stdint.h>

typedef __bf16 bf16;
typedef __bf16 bf16x4 __attribute__((ext_vector_type(4)));
typedef __bf16 bf16x8 __attribute__((ext_vector_type(8)));
typedef float  f32x4  __attribute__((ext_vector_type(4)));

#define DIM   768
#define HEADS 12
#define HD    64
#define SEQ   4096
#define NKT   24   // 768 / BK32

// ---- async global->LDS, 16B per lane ----
__device__ __forceinline__ void gload16(const void* g, void* l) {
  typedef const __attribute__((address_space(1))) uint32_t* gp_t;
  typedef __attribute__((address_space(3))) uint32_t* lp_t;
  gp_t gp = reinterpret_cast<gp_t>(reinterpret_cast<uintptr_t>(g));
  lp_t lp = reinterpret_cast<lp_t>(reinterpret_cast<uintptr_t>(l));
  __builtin_amdgcn_global_load_lds(gp, lp, 16, 0, 0);
}

// ---- weight fp32 -> bf16 convert ----
__global__ __launch_bounds__(256) void wcvt_kernel(const float* __restrict__ src,
                                                   bf16* __restrict__ dst) {
  int i = (blockIdx.x * 256 + threadIdx.x) * 4;
  float4 v = *reinterpret_cast<const float4*>(src + i);
  bf16x4 o;
  o[0] = (bf16)v.x; o[1] = (bf16)v.y; o[2] = (bf16)v.z; o[3] = (bf16)v.w;
  *reinterpret_cast<bf16x4*>(dst + i) = o;
}

// ---- LayerNorm: one wave per row, fp32 stats, bf16 out ----
__global__ __launch_bounds__(256) void ln_kernel(const float* __restrict__ x,
    const float* __restrict__ gam, const float* __restrict__ bet,
    bf16* __restrict__ y) {
  const int tid = threadIdx.x, w = tid >> 6, l = tid & 63;
  const int row = blockIdx.x * 4 + w;
  const float* xr = x + (long)row * DIM;
  float4 v[3];
  float s = 0.f, ss = 0.f;
#pragma unroll
  for (int j = 0; j < 3; j++) {
    v[j] = *reinterpret_cast<const float4*>(xr + l * 4 + j * 256);
    s  += v[j].x + v[j].y + v[j].z + v[j].w;
    ss += v[j].x * v[j].x + v[j].y * v[j].y + v[j].z * v[j].z + v[j].w * v[j].w;
  }
#pragma unroll
  for (int m = 1; m < 64; m <<= 1) { s += __shfl_xor(s, m); ss += __shfl_xor(ss, m); }
  const float mu = s * (1.f / 768.f);
  const float rstd = rsqrtf(ss * (1.f / 768.f) - mu * mu + 1e-5f);
  bf16* yr = y + (long)row * DIM;
#pragma unroll
  for (int j = 0; j < 3; j++) {
    int c = l * 4 + j * 256;
    float4 g4 = *reinterpret_cast<const float4*>(gam + c);
    float4 b4 = *reinterpret_cast<const float4*>(bet + c);
    bf16x4 o;
    o[0] = (bf16)((v[j].x - mu) * rstd * g4.x + b4.x);
    o[1] = (bf16)((v[j].y - mu) * rstd * g4.y + b4.y);
    o[2] = (bf16)((v[j].z - mu) * rstd * g4.z + b4.z);
    o[3] = (bf16)((v[j].w - mu) * rstd * g4.w + b4.w);
    *reinterpret_cast<bf16x4*>(yr + c) = o;
  }
}

// ---- 256x256 bf16 MFMA GEMM, C = A[M,768] * Bw[N,768]^T ----
// Deep pipeline: BK=32, ring-4 LDS, counted vmcnt (T4), raw s_barrier,
// T2 swizzle, T5 setprio, and register-fragment double-buffer so ds_reads
// (prefetch of phase p+1 / tile t+1) overlap MFMAs of phase p.
// MODE 0: qkv (elu+1 on q,k; scatter per-head), NT=9
// MODE 1: proj (+bias, fp32 out [t][768]), NT=3
template <int MODE>
__global__ __launch_bounds__(512, 2) void gemm_kernel(
    const bf16* __restrict__ A, const bf16* __restrict__ Bw,
    bf16* __restrict__ qb, bf16* __restrict__ kb, bf16* __restrict__ vb,
    float* __restrict__ outp, const float* __restrict__ bias) {
  // ring of 4 slots x 32KB: [A 256x32][B 256x32] bf16 each
  __shared__ __align__(16) char lds[131072];
  const int tid = threadIdx.x;
  const int wid = tid >> 6, l = tid & 63;
  const int wr = wid >> 2, wc = wid & 3;      // 2 x 4 wave grid
  const int l16 = l & 15, l4 = l >> 4;

  const int NT = (MODE == 0) ? 9 : 3;
  const int nwg = NT * 128;                    // M-tiles = 128
  const int orig = blockIdx.x;
  const int wgid = (orig & 7) * (nwg >> 3) + (orig >> 3);  // T1 bijective
  const int mt = wgid / NT, nt = wgid % NT;

  // ---- staging: loop-invariant addressing hoisted ----
  const bf16* gA[2]; const bf16* gB[2]; int ldso[2];
#pragma unroll
  for (int g = 0; g < 2; g++) {
    int L = g * 8192 + tid * 16;
    int r = L >> 6;                               // row (64B rows)
    int ce = ((L & 63) ^ (((L >> 7) & 3) << 4)) >> 1;  // inv-swizzled elem col
    gA[g] = A + (long)(mt * 256 + r) * DIM + ce;
    gB[g] = Bw + (long)(nt * 256 + r) * DIM + ce;
    ldso[g] = L;
  }
  auto STAGE = [&](int t) {
    const int slot = (t & 3) * 32768;
    const int k0 = t * 32;
#pragma unroll
    for (int g = 0; g < 2; g++) {
      gload16(gA[g] + k0, lds + slot + ldso[g]);
      gload16(gB[g] + k0, lds + slot + 16384 + ldso[g]);
    }
  };

  // ---- fragment LDS offsets (swizzled), loop-invariant ----
  int offA[8], offB[4];
#pragma unroll
  for (int mi = 0; mi < 8; mi++) {
    int off = (wr * 128 + mi * 16 + l16) * 64 + l4 * 16;
    offA[mi] = off ^ (((off >> 7) & 3) << 4);
  }
#pragma unroll
  for (int ni = 0; ni < 4; ni++) {
    int off = (wc * 64 + ni * 16 + l16) * 64 + l4 * 16;
    offB[ni] = 16384 + (off ^ (((off >> 7) & 3) << 4));
  }

  f32x4 acc[8][4];
#pragma unroll
  for (int m = 0; m < 8; m++)
#pragma unroll
    for (int n = 0; n < 4; n++) { f32x4 z4 = {0.f, 0.f, 0.f, 0.f}; acc[m][n] = z4; }

  STAGE(0); STAGE(1); STAGE(2);
  asm volatile("s_waitcnt vmcnt(8)" ::: "memory");   // tile 0 landed
  __builtin_amdgcn_s_barrier();
  asm volatile("" ::: "memory");

  bf16x8 ac[2], an[2], bc[4], bn[4];
#pragma unroll
  for (int ni = 0; ni < 4; ni++) bc[ni] = *reinterpret_cast<const bf16x8*>(lds + offB[ni]);
  ac[0] = *reinterpret_cast<const bf16x8*>(lds + offA[0]);
  ac[1] = *reinterpret_cast<const bf16x8*>(lds + offA[1]);

  for (int t = 0; t < NKT; t++) {
    const int slot = (t & 3) * 32768;
    const int slotn = ((t + 1) & 3) * 32768;
    // barrier A: all waves' reads of slot t-1 completed (consumed by MFMAs
    // before this point). Raw barrier: prefetch DMA stays in flight.
    __builtin_amdgcn_s_barrier();
    if (t + 3 < NKT) STAGE(t + 3);   // overwrites slot (t-1)&3 -- safe
    const int C = (t + 3 < NKT) ? 3 : (NKT - 1 - t);  // tiles staged ahead of t
    if (C >= 3)      asm volatile("s_waitcnt vmcnt(8)" ::: "memory");
    else if (C == 2) asm volatile("s_waitcnt vmcnt(4)" ::: "memory");
    else             asm volatile("s_waitcnt vmcnt(0)" ::: "memory");
    // barrier B: tiles t AND t+1 have landed for all waves.
    __builtin_amdgcn_s_barrier();
    asm volatile("" ::: "memory");          // no LDS-read hoist above barrier
    __builtin_amdgcn_sched_barrier(0);
    __builtin_amdgcn_s_setprio(1);
#pragma unroll
    for (int p = 0; p < 4; p++) {
      // prefetch next phase's A-pair (or next tile's B + pair0) -- these
      // ds_reads overlap the MFMAs below (no dependency until next phase).
      if (p < 3) {
        an[0] = *reinterpret_cast<const bf16x8*>(lds + slot + offA[2 * p + 2]);
        an[1] = *reinterpret_cast<const bf16x8*>(lds + slot + offA[2 * p + 3]);
      } else if (t + 1 < NKT) {
#pragma unroll
        for (int ni = 0; ni < 4; ni++)
          bn[ni] = *reinterpret_cast<const bf16x8*>(lds + slotn + offB[ni]);
        an[0] = *reinterpret_cast<const bf16x8*>(lds + slotn + offA[0]);
        an[1] = *reinterpret_cast<const bf16x8*>(lds + slotn + offA[1]);
      }
#pragma unroll
      for (int mi2 = 0; mi2 < 2; mi2++)
#pragma unroll
        for (int ni = 0; ni < 4; ni++)
          acc[2 * p + mi2][ni] = __builtin_amdgcn_mfma_f32_16x16x32_bf16(
              ac[mi2], bc[ni], acc[2 * p + mi2][ni], 0, 0, 0);
      ac[0] = an[0]; ac[1] = an[1];
    }
#pragma unroll
    for (int ni = 0; ni < 4; ni++) bc[ni] = bn[ni];
    __builtin_amdgcn_s_setprio(0);
  }

  if constexpr (MODE == 0) {
    // epilogue: reuse ring LDS as Cs[256][128] bf16 (64KB), 2 column passes
    bf16* Cs = (bf16*)lds;
    const int s = nt / 3;   // 0=q,1=k,2=v
    const int j = nt % 3;   // head group base j*4
    bf16* dst0 = (s == 0) ? qb : (s == 1) ? kb : vb;
#pragma unroll
    for (int p = 0; p < 2; p++) {
      __syncthreads();
      if ((wc >> 1) == p) {
#pragma unroll
        for (int mi = 0; mi < 8; mi++)
#pragma unroll
          for (int ni = 0; ni < 4; ni++)
#pragma unroll
            for (int i = 0; i < 4; i++) {
              float val = acc[mi][ni][i];
              if (s < 2) val = val > 0.f ? val + 1.f : __expf(val);
              int row = wr * 128 + mi * 16 + l4 * 4 + i;
              int col = (wc & 1) * 64 + ni * 16 + l16;
              Cs[row * 128 + col] = (bf16)val;
            }
      }
      __syncthreads();
#pragma unroll
      for (int it = 0; it < 8; it++) {
        int bi = it * 8192 + tid * 16;
        int row = bi >> 8;
        int col = (bi & 255) >> 1;
        int hh = 2 * p + (col >> 6), d = col & 63;
        int trow = mt * 256 + row;
        int bb = trow >> 12, tok = trow & 4095;
        *reinterpret_cast<bf16x8*>(dst0 +
            ((long)(bb * HEADS + j * 4 + hh) * SEQ + tok) * HD + d) =
            *reinterpret_cast<const bf16x8*>(Cs + (bi >> 1));
      }
    }
  } else {
#pragma unroll
    for (int ni = 0; ni < 4; ni++) {
      int col = nt * 256 + wc * 64 + ni * 16 + l16;
      float bv = bias[col];
#pragma unroll
      for (int mi = 0; mi < 8; mi++)
#pragma unroll
        for (int i = 0; i < 4; i++) {
          long trow = mt * 256 + wr * 128 + mi * 16 + l4 * 4 + i;
          outp[trow * DIM + col] = acc[mi][ni][i] + bv;
        }
    }
  }
}

// ---- kv partials: per (head, split of 512 tokens): kv[64][64] += k^T v ; ksum ----
__global__ __launch_bounds__(256) void kv_kernel(
    const bf16* __restrict__ kb, const bf16* __restrict__ vb,
    float* __restrict__ kv_part, float* __restrict__ ks_part) {
  __shared__ __align__(16) union UU {
    struct { bf16 Ks[128 * 64]; bf16 Vs[128 * 64]; } s;
    float red[8192];
  } u;
  __shared__ float ksred[4][64];
  const int head = blockIdx.x, sp = blockIdx.y;
  const int tid = threadIdx.x, w = tid >> 6, l = tid & 63;
  const int d0 = (l >> 3) * 8, e0 = (l & 7) * 8;
  const bf16* K = kb + (long)(head * SEQ + sp * 512) * HD;
  const bf16* V = vb + (long)(head * SEQ + sp * 512) * HD;
  float acc[8][8];
#pragma unroll
  for (int i = 0; i < 8; i++)
#pragma unroll
    for (int jj = 0; jj < 8; jj++) acc[i][jj] = 0.f;
  float ks[8] = {0.f, 0.f, 0.f, 0.f, 0.f, 0.f, 0.f, 0.f};

  for (int t0 = 0; t0 < 512; t0 += 128) {
    __syncthreads();
#pragma unroll
    for (int r = 0; r < 4; r++) {
      gload16(K + t0 * 64 + r * 2048 + tid * 8, u.s.Ks + r * 2048 + tid * 8);
      gload16(V + t0 * 64 + r * 2048 + tid * 8, u.s.Vs + r * 2048 + tid * 8);
    }
    __syncthreads();
    for (int n = w * 32; n < w * 32 + 32; n++) {
      bf16x8 k8 = *reinterpret_cast<const bf16x8*>(u.s.Ks + n * 64 + d0);
      bf16x8 v8 = *reinterpret_cast<const bf16x8*>(u.s.Vs + n * 64 + e0);
      float kf[8], vf[8];
#pragma unroll
      for (int i = 0; i < 8; i++) { kf[i] = (float)k8[i]; vf[i] = (float)v8[i]; }
#pragma unroll
      for (int i = 0; i < 8; i++) {
        ks[i] += kf[i];
#pragma unroll
        for (int jj = 0; jj < 8; jj++) acc[i][jj] += kf[i] * vf[jj];
      }
    }
  }
  if ((l & 7) == 0) {
#pragma unroll
    for (int i = 0; i < 8; i++) ksred[w][d0 + i] = ks[i];
  }
  __syncthreads();
  if (w >= 2) {
    float* dst = u.red + (w - 2) * 4096;
#pragma unroll
    for (int i = 0; i < 8; i++) {
      f32x4 a = {acc[i][0], acc[i][1], acc[i][2], acc[i][3]};
      f32x4 b = {acc[i][4], acc[i][5], acc[i][6], acc[i][7]};
      *reinterpret_cast<f32x4*>(dst + (d0 + i) * 64 + e0) = a;
      *reinterpret_cast<f32x4*>(dst + (d0 + i) * 64 + e0 + 4) = b;
    }
  }
  __syncthreads();
  if (w < 2) {
    const float* src = u.red + w * 4096;
#pragma unroll
    for (int i = 0; i < 8; i++)
#pragma unroll
      for (int jj = 0; jj < 8; jj++) acc[i][jj] += src[(d0 + i) * 64 + e0 + jj];
  }
  __syncthreads();
  if (w == 1) {
    float* dst = u.red;
#pragma unroll
    for (int i = 0; i < 8; i++) {
      f32x4 a = {acc[i][0], acc[i][1], acc[i][2], acc[i][3]};
      f32x4 b = {acc[i][4], acc[i][5], acc[i][6], acc[i][7]};
      *reinterpret_cast<f32x4*>(dst + (d0 + i) * 64 + e0) = a;
      *reinterpret_cast<f32x4*>(dst + (d0 + i) * 64 + e0 + 4) = b;
    }
  }
  __syncthreads();
  if (w == 0) {
    const float* src = u.red;
#pragma unroll
    for (int i = 0; i < 8; i++)
#pragma unroll
      for (int jj = 0; jj < 8; jj++) acc[i][jj] += src[(d0 + i) * 64 + e0 + jj];
    float* dst = kv_part + (long)(head * 8 + sp) * 4096;
#pragma unroll
    for (int i = 0; i < 8; i++) {
      f32x4 a = {acc[i][0], acc[i][1], acc[i][2], acc[i][3]};
      f32x4 b = {acc[i][4], acc[i][5], acc[i][6], acc[i][7]};
      *reinterpret_cast<f32x4*>(dst + (d0 + i) * 64 + e0) = a;
      *reinterpret_cast<f32x4*>(dst + (d0 + i) * 64 + e0 + 4) = b;
    }
  }
  if (tid < 64)
    ks_part[(head * 8 + sp) * 64 + tid] =
        ksred[0][tid] + ksred[1][tid] + ksred[2][tid] + ksred[3][tid];
}

// ---- finalize: sum partials -> kvT bf16 [head][e][d], ksum fp32 [head][d] ----
__global__ __launch_bounds__(256) void kvfin_kernel(const float* __restrict__ kv_part,
    const float* __restrict__ ks_part, bf16* __restrict__ kvT, float* __restrict__ ksum) {
  const int head = blockIdx.x, tid = threadIdx.x;
  const long base = (long)head * 8 * 4096;
  const int d = tid >> 2, ecol = (tid & 3) * 16;
  float s[16];
#pragma unroll
  for (int q = 0; q < 16; q++) s[q] = 0.f;
  for (int sp = 0; sp < 8; sp++) {
    const float* p = kv_part + base + sp * 4096 + d * 64 + ecol;
#pragma unroll
    for (int q = 0; q < 16; q++) s[q] += p[q];
  }
#pragma unroll
  for (int q = 0; q < 16; q++) kvT[head * 4096 + (ecol + q) * 64 + d] = (bf16)s[q];
  if (tid < 64) {
    float t = 0.f;
    for (int sp = 0; sp < 8; sp++) t += ks_part[(head * 8 + sp) * 64 + tid];
    ksum[head * 64 + tid] = t;
  }
}

// ---- out_pre = (Q @ kv) * z, bf16 out in [t][768] layout ----
__global__ __launch_bounds__(256) void qout_kernel(const bf16* __restrict__ qb,
    const bf16* __restrict__ kvT, const float* __restrict__ ksum,
    bf16* __restrict__ outp) {
  __shared__ __align__(16) bf16 Qs[128 * 64];
  __shared__ __align__(16) bf16 Bs2[64 * 64];
  __shared__ float ksum_s[64];
  __shared__ float z_s[128];
  const int head = blockIdx.x, tt = blockIdx.y;
  const int b = head / HEADS, h = head % HEADS;
  const int tid = threadIdx.x, w = tid >> 6, l = tid & 63;
  const int l16 = l & 15, l4 = l >> 4;
  const bf16* Qg = qb + (long)(head * SEQ + tt * 128) * HD;
#pragma unroll
  for (int r = 0; r < 4; r++) gload16(Qg + r * 2048 + tid * 8, Qs + r * 2048 + tid * 8);
#pragma unroll
  for (int r = 0; r < 2; r++)
    gload16(kvT + head * 4096 + r * 2048 + tid * 8, Bs2 + r * 2048 + tid * 8);
  if (tid < 64) ksum_s[tid] = ksum[head * 64 + tid];
  __syncthreads();
  if (tid < 128) {
    float dsum = 0.f;
#pragma unroll
    for (int i = 0; i < 8; i++) {
      bf16x8 q8 = *reinterpret_cast<const bf16x8*>(Qg + tid * 64 + i * 8);
#pragma unroll
      for (int jj = 0; jj < 8; jj++) dsum += (float)q8[jj] * ksum_s[i * 8 + jj];
    }
    z_s[tid] = 1.f / (dsum + 1e-6f);
  }
  f32x4 acc[2][4];
#pragma unroll
  for (int m = 0; m < 2; m++)
#pragma unroll
    for (int n = 0; n < 4; n++) { f32x4 z4 = {0.f, 0.f, 0.f, 0.f}; acc[m][n] = z4; }
#pragma unroll
  for (int kk = 0; kk < 2; kk++) {
    bf16x8 af[2], bfr[4];
#pragma unroll
    for (int m = 0; m < 2; m++)
      af[m] = *reinterpret_cast<const bf16x8*>(Qs + (w * 32 + m * 16 + l16) * 64 + kk * 32 + l4 * 8);
#pragma unroll
    for (int n = 0; n < 4; n++)
      bfr[n] = *reinterpret_cast<const bf16x8*>(Bs2 + (n * 16 + l16) * 64 + kk * 32 + l4 * 8);
#pragma unroll
    for (int m = 0; m < 2; m++)
#pragma unroll
      for (int n = 0; n < 4; n++)
        acc[m][n] = __builtin_amdgcn_mfma_f32_16x16x32_bf16(af[m], bfr[n], acc[m][n], 0, 0, 0);
  }
  __syncthreads();
#pragma unroll
  for (int m = 0; m < 2; m++)
#pragma unroll
    for (int n = 0; n < 4; n++)
#pragma unroll
      for (int i = 0; i < 4; i++) {
        int row = w * 32 + m * 16 + l4 * 4 + i;
        Qs[row * 64 + n * 16 + l16] = (bf16)(acc[m][n][i] * z_s[row]);
      }
  __syncthreads();
#pragma unroll
  for (int r = 0; r < 4; r++) {
    int idx = r * 2048 + tid * 8;
    int row = idx >> 6, col = idx & 63;
    *reinterpret_cast<bf16x8*>(outp + (long)(b * SEQ + tt * 128 + row) * DIM + h * HD + col) =
        *reinterpret_cast<const bf16x8*>(Qs + idx);
  }
}

extern "C" void kernel_launch(void* const* d_in, const int* in_sizes, int n_in,
                              void* d_out, int out_size, void* d_ws, size_t ws_size,
                              hipStream_t stream) {
  const float* x     = (const float*)d_in[0];
  const float* gam   = (const float*)d_in[1];
  const float* bet   = (const float*)d_in[2];
  const float* wqkv  = (const float*)d_in[3];
  const float* wproj = (const float*)d_in[4];
  const float* bproj = (const float*)d_in[5];
  float* out = (float*)d_out;
  char* ws = (char*)d_ws;

  bf16*  y       = (bf16*)(ws);                    // 50331648 B (reused as out_pre)
  bf16*  qb      = (bf16*)(ws + 50331648);         // 50331648 B
  bf16*  kb      = (bf16*)(ws + 100663296);        // 50331648 B
  bf16*  vb      = (bf16*)(ws + 150994944);        // 50331648 B
  bf16*  wqkv_b  = (bf16*)(ws + 201326592);        // 3538944 B
  bf16*  wproj_b = (bf16*)(ws + 204865536);        // 1179648 B
  float* kv_part = (float*)(ws + 206045184);       // 12582912 B
  float* ks_part = (float*)(ws + 218628096);       // 196608 B
  bf16*  kvT     = (bf16*)(ws + 218824704);        // 786432 B
  float* ksum    = (float*)(ws + 219611136);       // 24576 B

  wcvt_kernel<<<1728, 256, 0, stream>>>(wqkv, wqkv_b);
  wcvt_kernel<<<576, 256, 0, stream>>>(wproj, wproj_b);
  ln_kernel<<<8192, 256, 0, stream>>>(x, gam, bet, y);
  gemm_kernel<0><<<dim3(9 * 128), 512, 0, stream>>>(y, wqkv_b, qb, kb, vb, nullptr, nullptr);
  kv_kernel<<<dim3(96, 8), 256, 0, stream>>>(kb, vb, kv_part, ks_part);
  kvfin_kernel<<<96, 256, 0, stream>>>(kv_part, ks_part, kvT, ksum);
  qout_kernel<<<dim3(96, 32), 256, 0, stream>>>(qb, kvT, ksum, y);
  gemm_kernel<1><<<dim3(3 * 128), 512, 0, stream>>>(y, wproj_b, nullptr, nullptr, nullptr, out, bproj);
}

// Round 6
// 335.743 us; speedup vs baseline: 1.1757x; 1.0108x over previous
//
#include <hip/hip_runtime.h>
#include <stdint.h>

typedef __bf16 bf16;
typedef __bf16 bf16x4 __attribute__((ext_vector_type(4)));
typedef __bf16 bf16x8 __attribute__((ext_vector_type(8)));
typedef float  f32x4  __attribute__((ext_vector_type(4)));

#define DIM   768
#define HEADS 12
#define HD    64
#define SEQ   4096
#define NKT   24   // 768 / BK32

// ---- async global->LDS, 16B per lane ----
__device__ __forceinline__ void gload16(const void* g, void* l) {
  typedef const __attribute__((address_space(1))) uint32_t* gp_t;
  typedef __attribute__((address_space(3))) uint32_t* lp_t;
  gp_t gp = reinterpret_cast<gp_t>(reinterpret_cast<uintptr_t>(g));
  lp_t lp = reinterpret_cast<lp_t>(reinterpret_cast<uintptr_t>(l));
  __builtin_amdgcn_global_load_lds(gp, lp, 16, 0, 0);
}

// ---- weight fp32 -> bf16 convert ----
__global__ __launch_bounds__(256) void wcvt_kernel(const float* __restrict__ src,
                                                   bf16* __restrict__ dst) {
  int i = (blockIdx.x * 256 + threadIdx.x) * 4;
  float4 v = *reinterpret_cast<const float4*>(src + i);
  bf16x4 o;
  o[0] = (bf16)v.x; o[1] = (bf16)v.y; o[2] = (bf16)v.z; o[3] = (bf16)v.w;
  *reinterpret_cast<bf16x4*>(dst + i) = o;
}

// ---- LayerNorm: one wave per row, fp32 stats, bf16 out ----
__global__ __launch_bounds__(256) void ln_kernel(const float* __restrict__ x,
    const float* __restrict__ gam, const float* __restrict__ bet,
    bf16* __restrict__ y) {
  const int tid = threadIdx.x, w = tid >> 6, l = tid & 63;
  const int row = blockIdx.x * 4 + w;
  const float* xr = x + (long)row * DIM;
  float4 v[3];
  float s = 0.f, ss = 0.f;
#pragma unroll
  for (int j = 0; j < 3; j++) {
    v[j] = *reinterpret_cast<const float4*>(xr + l * 4 + j * 256);
    s  += v[j].x + v[j].y + v[j].z + v[j].w;
    ss += v[j].x * v[j].x + v[j].y * v[j].y + v[j].z * v[j].z + v[j].w * v[j].w;
  }
#pragma unroll
  for (int m = 1; m < 64; m <<= 1) { s += __shfl_xor(s, m); ss += __shfl_xor(ss, m); }
  const float mu = s * (1.f / 768.f);
  const float rstd = rsqrtf(ss * (1.f / 768.f) - mu * mu + 1e-5f);
  bf16* yr = y + (long)row * DIM;
#pragma unroll
  for (int j = 0; j < 3; j++) {
    int c = l * 4 + j * 256;
    float4 g4 = *reinterpret_cast<const float4*>(gam + c);
    float4 b4 = *reinterpret_cast<const float4*>(bet + c);
    bf16x4 o;
    o[0] = (bf16)((v[j].x - mu) * rstd * g4.x + b4.x);
    o[1] = (bf16)((v[j].y - mu) * rstd * g4.y + b4.y);
    o[2] = (bf16)((v[j].z - mu) * rstd * g4.z + b4.z);
    o[3] = (bf16)((v[j].w - mu) * rstd * g4.w + b4.w);
    *reinterpret_cast<bf16x4*>(yr + c) = o;
  }
}

// ---- 256x256 bf16 MFMA GEMM, C = A[M,768] * Bw[N,768]^T ----
// Fine-phase schedule (m201-class): BK=32, ring-3 LDS (96KB), 2 sub-phases
// per K-tile, per-phase {ds_read; stage; barrier; lgkm0; 16 MFMA; barrier},
// tile-boundary counted vmcnt(4) (never 0 mid-loop). T1+T2+T5.
// MODE 0: qkv (elu+1 on q,k; scatter per-head), NT=9
// MODE 1: proj (+bias, fp32 out [t][768]), NT=3
template <int MODE>
__global__ __launch_bounds__(512, 2) void gemm_kernel(
    const bf16* __restrict__ A, const bf16* __restrict__ Bw,
    bf16* __restrict__ qb, bf16* __restrict__ kb, bf16* __restrict__ vb,
    float* __restrict__ outp, const float* __restrict__ bias) {
  // ring of 3 slots x 32KB: [A 256x32 | B 256x32] bf16, row stride 64B
  __shared__ __align__(16) char lds[98304];
  const int tid = threadIdx.x;
  const int wid = tid >> 6, l = tid & 63;
  const int wr = wid >> 2, wc = wid & 3;      // 2 x 4 wave grid
  const int l16 = l & 15, l4 = l >> 4;

  const int NT = (MODE == 0) ? 9 : 3;
  const int nwg = NT * 128;                    // M-tiles = 128
  const int orig = blockIdx.x;
  const int wgid = (orig & 7) * (nwg >> 3) + (orig >> 3);  // T1 bijective
  const int mt = wgid / NT, nt = wgid % NT;

  // ---- staging pointers (2 chunks each for A and B), loop-invariant ----
  const bf16* pA[2]; const bf16* pB[2]; int lo[2];
#pragma unroll
  for (int g = 0; g < 2; g++) {
    int L = g * 8192 + tid * 16;
    int r = L >> 6;                                     // row (64B rows)
    int ce = ((L & 63) ^ (((L >> 7) & 3) << 4)) >> 1;   // inv-swizzled elem col
    pA[g] = A + (long)(mt * 256 + r) * DIM + ce;
    pB[g] = Bw + (long)(nt * 256 + r) * DIM + ce;
    lo[g] = L;
  }

  // ---- fragment LDS offsets (swizzled, slot-local) ----
  int offA[8], offB[4];
#pragma unroll
  for (int mi = 0; mi < 8; mi++) {
    int off = (wr * 128 + mi * 16 + l16) * 64 + l4 * 16;
    offA[mi] = off ^ (((off >> 7) & 3) << 4);
  }
#pragma unroll
  for (int ni = 0; ni < 4; ni++) {
    int off = (wc * 64 + ni * 16 + l16) * 64 + l4 * 16;
    offB[ni] = 16384 + (off ^ (((off >> 7) & 3) << 4));
  }

  f32x4 acc[8][4];
#pragma unroll
  for (int m = 0; m < 8; m++)
#pragma unroll
    for (int n = 0; n < 4; n++) { f32x4 z4 = {0.f, 0.f, 0.f, 0.f}; acc[m][n] = z4; }

  // ---- prologue: stage tiles 0,1; wait tile 0 (counted) ----
#pragma unroll
  for (int g = 0; g < 2; g++) { gload16(pA[g], lds + lo[g]); gload16(pB[g], lds + 16384 + lo[g]); }
#pragma unroll
  for (int g = 0; g < 2; g++) { gload16(pA[g] + 32, lds + 32768 + lo[g]); gload16(pB[g] + 32, lds + 32768 + 16384 + lo[g]); }
  asm volatile("s_waitcnt vmcnt(4)" ::: "memory");   // tile 0 landed
  __builtin_amdgcn_s_barrier();

  int slot = 0;           // byte base of current ring slot
  int slot2 = 65536;      // byte base of slot for tile t+2
  for (int t = 0; t < NKT; t++) {
    const int k2 = (t + 2) * 32;
    const bool st = (t + 2 < NKT);
    bf16x8 a0[4], a1[4], bc[4];
    // ===== sub-phase 0: reads (B all + A lower) | stage chunk 0 | MFMA mi0-3
#pragma unroll
    for (int ni = 0; ni < 4; ni++) bc[ni] = *reinterpret_cast<const bf16x8*>(lds + slot + offB[ni]);
#pragma unroll
    for (int j = 0; j < 4; j++) a0[j] = *reinterpret_cast<const bf16x8*>(lds + slot + offA[j]);
    if (st) { gload16(pA[0] + k2, lds + slot2 + lo[0]); gload16(pB[0] + k2, lds + slot2 + 16384 + lo[0]); }
    __builtin_amdgcn_s_barrier();
    asm volatile("s_waitcnt lgkmcnt(0)" ::: "memory");
    __builtin_amdgcn_sched_barrier(0);
    __builtin_amdgcn_s_setprio(1);
#pragma unroll
    for (int mi = 0; mi < 4; mi++)
#pragma unroll
      for (int ni = 0; ni < 4; ni++)
        acc[mi][ni] = __builtin_amdgcn_mfma_f32_16x16x32_bf16(a0[mi], bc[ni], acc[mi][ni], 0, 0, 0);
    __builtin_amdgcn_s_setprio(0);
    __builtin_amdgcn_s_barrier();
    // ===== sub-phase 1: reads (A upper) | stage chunk 1 | MFMA mi4-7
#pragma unroll
    for (int j = 0; j < 4; j++) a1[j] = *reinterpret_cast<const bf16x8*>(lds + slot + offA[4 + j]);
    if (st) { gload16(pA[1] + k2, lds + slot2 + lo[1]); gload16(pB[1] + k2, lds + slot2 + 16384 + lo[1]); }
    __builtin_amdgcn_s_barrier();
    asm volatile("s_waitcnt lgkmcnt(0)" ::: "memory");
    __builtin_amdgcn_sched_barrier(0);
    __builtin_amdgcn_s_setprio(1);
#pragma unroll
    for (int mi = 0; mi < 4; mi++)
#pragma unroll
      for (int ni = 0; ni < 4; ni++)
        acc[4 + mi][ni] = __builtin_amdgcn_mfma_f32_16x16x32_bf16(a1[mi], bc[ni], acc[4 + mi][ni], 0, 0, 0);
    __builtin_amdgcn_s_setprio(0);
    // ===== tile boundary: counted wait so tile t+1 is landed for everyone
    if (t < NKT - 2)      asm volatile("s_waitcnt vmcnt(4)" ::: "memory");
    else if (t == NKT - 2) asm volatile("s_waitcnt vmcnt(0)" ::: "memory");
    __builtin_amdgcn_s_barrier();
    slot = (slot == 65536) ? 0 : slot + 32768;
    slot2 = (slot2 == 65536) ? 0 : slot2 + 32768;
  }

  if constexpr (MODE == 0) {
    // epilogue: reuse ring LDS as Cs[256][128] bf16 (64KB), 2 column passes
    bf16* Cs = (bf16*)lds;
    const int s = nt / 3;   // 0=q,1=k,2=v
    const int j = nt % 3;   // head group base j*4
    bf16* dst0 = (s == 0) ? qb : (s == 1) ? kb : vb;
#pragma unroll
    for (int p = 0; p < 2; p++) {
      __syncthreads();
      if ((wc >> 1) == p) {
#pragma unroll
        for (int mi = 0; mi < 8; mi++)
#pragma unroll
          for (int ni = 0; ni < 4; ni++)
#pragma unroll
            for (int i = 0; i < 4; i++) {
              float val = acc[mi][ni][i];
              if (s < 2) val = val > 0.f ? val + 1.f : __expf(val);
              int row = wr * 128 + mi * 16 + l4 * 4 + i;
              int col = (wc & 1) * 64 + ni * 16 + l16;
              Cs[row * 128 + col] = (bf16)val;
            }
      }
      __syncthreads();
#pragma unroll
      for (int it = 0; it < 8; it++) {
        int bi = it * 8192 + tid * 16;
        int row = bi >> 8;
        int col = (bi & 255) >> 1;
        int hh = 2 * p + (col >> 6), d = col & 63;
        int trow = mt * 256 + row;
        int bb = trow >> 12, tok = trow & 4095;
        *reinterpret_cast<bf16x8*>(dst0 +
            ((long)(bb * HEADS + j * 4 + hh) * SEQ + tok) * HD + d) =
            *reinterpret_cast<const bf16x8*>(Cs + (bi >> 1));
      }
    }
  } else {
#pragma unroll
    for (int ni = 0; ni < 4; ni++) {
      int col = nt * 256 + wc * 64 + ni * 16 + l16;
      float bv = bias[col];
#pragma unroll
      for (int mi = 0; mi < 8; mi++)
#pragma unroll
        for (int i = 0; i < 4; i++) {
          long trow = mt * 256 + wr * 128 + mi * 16 + l4 * 4 + i;
          outp[trow * DIM + col] = acc[mi][ni][i] + bv;
        }
    }
  }
}

// ---- kv partials: per (head, split of 512 tokens): kv[64][64] += k^T v ; ksum ----
__global__ __launch_bounds__(256) void kv_kernel(
    const bf16* __restrict__ kb, const bf16* __restrict__ vb,
    float* __restrict__ kv_part, float* __restrict__ ks_part) {
  __shared__ __align__(16) union UU {
    struct { bf16 Ks[128 * 64]; bf16 Vs[128 * 64]; } s;
    float red[8192];
  } u;
  __shared__ float ksred[4][64];
  const int head = blockIdx.x, sp = blockIdx.y;
  const int tid = threadIdx.x, w = tid >> 6, l = tid & 63;
  const int d0 = (l >> 3) * 8, e0 = (l & 7) * 8;
  const bf16* K = kb + (long)(head * SEQ + sp * 512) * HD;
  const bf16* V = vb + (long)(head * SEQ + sp * 512) * HD;
  float acc[8][8];
#pragma unroll
  for (int i = 0; i < 8; i++)
#pragma unroll
    for (int jj = 0; jj < 8; jj++) acc[i][jj] = 0.f;
  float ks[8] = {0.f, 0.f, 0.f, 0.f, 0.f, 0.f, 0.f, 0.f};

  for (int t0 = 0; t0 < 512; t0 += 128) {
    __syncthreads();
#pragma unroll
    for (int r = 0; r < 4; r++) {
      gload16(K + t0 * 64 + r * 2048 + tid * 8, u.s.Ks + r * 2048 + tid * 8);
      gload16(V + t0 * 64 + r * 2048 + tid * 8, u.s.Vs + r * 2048 + tid * 8);
    }
    __syncthreads();
    for (int n = w * 32; n < w * 32 + 32; n++) {
      bf16x8 k8 = *reinterpret_cast<const bf16x8*>(u.s.Ks + n * 64 + d0);
      bf16x8 v8 = *reinterpret_cast<const bf16x8*>(u.s.Vs + n * 64 + e0);
      float kf[8], vf[8];
#pragma unroll
      for (int i = 0; i < 8; i++) { kf[i] = (float)k8[i]; vf[i] = (float)v8[i]; }
#pragma unroll
      for (int i = 0; i < 8; i++) {
        ks[i] += kf[i];
#pragma unroll
        for (int jj = 0; jj < 8; jj++) acc[i][jj] += kf[i] * vf[jj];
      }
    }
  }
  if ((l & 7) == 0) {
#pragma unroll
    for (int i = 0; i < 8; i++) ksred[w][d0 + i] = ks[i];
  }
  __syncthreads();
  if (w >= 2) {
    float* dst = u.red + (w - 2) * 4096;
#pragma unroll
    for (int i = 0; i < 8; i++) {
      f32x4 a = {acc[i][0], acc[i][1], acc[i][2], acc[i][3]};
      f32x4 b = {acc[i][4], acc[i][5], acc[i][6], acc[i][7]};
      *reinterpret_cast<f32x4*>(dst + (d0 + i) * 64 + e0) = a;
      *reinterpret_cast<f32x4*>(dst + (d0 + i) * 64 + e0 + 4) = b;
    }
  }
  __syncthreads();
  if (w < 2) {
    const float* src = u.red + w * 4096;
#pragma unroll
    for (int i = 0; i < 8; i++)
#pragma unroll
      for (int jj = 0; jj < 8; jj++) acc[i][jj] += src[(d0 + i) * 64 + e0 + jj];
  }
  __syncthreads();
  if (w == 1) {
    float* dst = u.red;
#pragma unroll
    for (int i = 0; i < 8; i++) {
      f32x4 a = {acc[i][0], acc[i][1], acc[i][2], acc[i][3]};
      f32x4 b = {acc[i][4], acc[i][5], acc[i][6], acc[i][7]};
      *reinterpret_cast<f32x4*>(dst + (d0 + i) * 64 + e0) = a;
      *reinterpret_cast<f32x4*>(dst + (d0 + i) * 64 + e0 + 4) = b;
    }
  }
  __syncthreads();
  if (w == 0) {
    const float* src = u.red;
#pragma unroll
    for (int i = 0; i < 8; i++)
#pragma unroll
      for (int jj = 0; jj < 8; jj++) acc[i][jj] += src[(d0 + i) * 64 + e0 + jj];
    float* dst = kv_part + (long)(head * 8 + sp) * 4096;
#pragma unroll
    for (int i = 0; i < 8; i++) {
      f32x4 a = {acc[i][0], acc[i][1], acc[i][2], acc[i][3]};
      f32x4 b = {acc[i][4], acc[i][5], acc[i][6], acc[i][7]};
      *reinterpret_cast<f32x4*>(dst + (d0 + i) * 64 + e0) = a;
      *reinterpret_cast<f32x4*>(dst + (d0 + i) * 64 + e0 + 4) = b;
    }
  }
  if (tid < 64)
    ks_part[(head * 8 + sp) * 64 + tid] =
        ksred[0][tid] + ksred[1][tid] + ksred[2][tid] + ksred[3][tid];
}

// ---- finalize: sum partials -> kvT bf16 [head][e][d], ksum fp32 [head][d] ----
__global__ __launch_bounds__(256) void kvfin_kernel(const float* __restrict__ kv_part,
    const float* __restrict__ ks_part, bf16* __restrict__ kvT, float* __restrict__ ksum) {
  const int head = blockIdx.x, tid = threadIdx.x;
  const long base = (long)head * 8 * 4096;
  const int d = tid >> 2, ecol = (tid & 3) * 16;
  float s[16];
#pragma unroll
  for (int q = 0; q < 16; q++) s[q] = 0.f;
  for (int sp = 0; sp < 8; sp++) {
    const float* p = kv_part + base + sp * 4096 + d * 64 + ecol;
#pragma unroll
    for (int q = 0; q < 16; q++) s[q] += p[q];
  }
#pragma unroll
  for (int q = 0; q < 16; q++) kvT[head * 4096 + (ecol + q) * 64 + d] = (bf16)s[q];
  if (tid < 64) {
    float t = 0.f;
    for (int sp = 0; sp < 8; sp++) t += ks_part[(head * 8 + sp) * 64 + tid];
    ksum[head * 64 + tid] = t;
  }
}

// ---- out_pre = (Q @ kv) * z, bf16 out in [t][768] layout ----
__global__ __launch_bounds__(256) void qout_kernel(const bf16* __restrict__ qb,
    const bf16* __restrict__ kvT, const float* __restrict__ ksum,
    bf16* __restrict__ outp) {
  __shared__ __align__(16) bf16 Qs[128 * 64];
  __shared__ __align__(16) bf16 Bs2[64 * 64];
  __shared__ float ksum_s[64];
  __shared__ float z_s[128];
  const int head = blockIdx.x, tt = blockIdx.y;
  const int b = head / HEADS, h = head % HEADS;
  const int tid = threadIdx.x, w = tid >> 6, l = tid & 63;
  const int l16 = l & 15, l4 = l >> 4;
  const bf16* Qg = qb + (long)(head * SEQ + tt * 128) * HD;
#pragma unroll
  for (int r = 0; r < 4; r++) gload16(Qg + r * 2048 + tid * 8, Qs + r * 2048 + tid * 8);
#pragma unroll
  for (int r = 0; r < 2; r++)
    gload16(kvT + head * 4096 + r * 2048 + tid * 8, Bs2 + r * 2048 + tid * 8);
  if (tid < 64) ksum_s[tid] = ksum[head * 64 + tid];
  __syncthreads();
  if (tid < 128) {
    float dsum = 0.f;
#pragma unroll
    for (int i = 0; i < 8; i++) {
      bf16x8 q8 = *reinterpret_cast<const bf16x8*>(Qg + tid * 64 + i * 8);
#pragma unroll
      for (int jj = 0; jj < 8; jj++) dsum += (float)q8[jj] * ksum_s[i * 8 + jj];
    }
    z_s[tid] = 1.f / (dsum + 1e-6f);
  }
  f32x4 acc[2][4];
#pragma unroll
  for (int m = 0; m < 2; m++)
#pragma unroll
    for (int n = 0; n < 4; n++) { f32x4 z4 = {0.f, 0.f, 0.f, 0.f}; acc[m][n] = z4; }
#pragma unroll
  for (int kk = 0; kk < 2; kk++) {
    bf16x8 af[2], bfr[4];
#pragma unroll
    for (int m = 0; m < 2; m++)
      af[m] = *reinterpret_cast<const bf16x8*>(Qs + (w * 32 + m * 16 + l16) * 64 + kk * 32 + l4 * 8);
#pragma unroll
    for (int n = 0; n < 4; n++)
      bfr[n] = *reinterpret_cast<const bf16x8*>(Bs2 + (n * 16 + l16) * 64 + kk * 32 + l4 * 8);
#pragma unroll
    for (int m = 0; m < 2; m++)
#pragma unroll
      for (int n = 0; n < 4; n++)
        acc[m][n] = __builtin_amdgcn_mfma_f32_16x16x32_bf16(af[m], bfr[n], acc[m][n], 0, 0, 0);
  }
  __syncthreads();
#pragma unroll
  for (int m = 0; m < 2; m++)
#pragma unroll
    for (int n = 0; n < 4; n++)
#pragma unroll
      for (int i = 0; i < 4; i++) {
        int row = w * 32 + m * 16 + l4 * 4 + i;
        Qs[row * 64 + n * 16 + l16] = (bf16)(acc[m][n][i] * z_s[row]);
      }
  __syncthreads();
#pragma unroll
  for (int r = 0; r < 4; r++) {
    int idx = r * 2048 + tid * 8;
    int row = idx >> 6, col = idx & 63;
    *reinterpret_cast<bf16x8*>(outp + (long)(b * SEQ + tt * 128 + row) * DIM + h * HD + col) =
        *reinterpret_cast<const bf16x8*>(Qs + idx);
  }
}

extern "C" void kernel_launch(void* const* d_in, const int* in_sizes, int n_in,
                              void* d_out, int out_size, void* d_ws, size_t ws_size,
                              hipStream_t stream) {
  const float* x     = (const float*)d_in[0];
  const float* gam   = (const float*)d_in[1];
  const float* bet   = (const float*)d_in[2];
  const float* wqkv  = (const float*)d_in[3];
  const float* wproj = (const float*)d_in[4];
  const float* bproj = (const float*)d_in[5];
  float* out = (float*)d_out;
  char* ws = (char*)d_ws;

  bf16*  y       = (bf16*)(ws);                    // 50331648 B (reused as out_pre)
  bf16*  qb      = (bf16*)(ws + 50331648);         // 50331648 B
  bf16*  kb      = (bf16*)(ws + 100663296);        // 50331648 B
  bf16*  vb      = (bf16*)(ws + 150994944);        // 50331648 B
  bf16*  wqkv_b  = (bf16*)(ws + 201326592);        // 3538944 B
  bf16*  wproj_b = (bf16*)(ws + 204865536);        // 1179648 B
  float* kv_part = (float*)(ws + 206045184);       // 12582912 B
  float* ks_part = (float*)(ws + 218628096);       // 196608 B
  bf16*  kvT     = (bf16*)(ws + 218824704);        // 786432 B
  float* ksum    = (float*)(ws + 219611136);       // 24576 B

  wcvt_kernel<<<1728, 256, 0, stream>>>(wqkv, wqkv_b);
  wcvt_kernel<<<576, 256, 0, stream>>>(wproj, wproj_b);
  ln_kernel<<<8192, 256, 0, stream>>>(x, gam, bet, y);
  gemm_kernel<0><<<dim3(9 * 128), 512, 0, stream>>>(y, wqkv_b, qb, kb, vb, nullptr, nullptr);
  kv_kernel<<<dim3(96, 8), 256, 0, stream>>>(kb, vb, kv_part, ks_part);
  kvfin_kernel<<<96, 256, 0, stream>>>(kv_part, ks_part, kvT, ksum);
  qout_kernel<<<dim3(96, 32), 256, 0, stream>>>(qb, kvT, ksum, y);
  gemm_kernel<1><<<dim3(3 * 128), 512, 0, stream>>>(y, wproj_b, nullptr, nullptr, nullptr, out, bproj);
}

// Round 7
// 323.717 us; speedup vs baseline: 1.2194x; 1.0371x over previous
//
#include <hip/hip_runtime.h>
#include <stdint.h>

typedef __bf16 bf16;
typedef __bf16 bf16x4 __attribute__((ext_vector_type(4)));
typedef __bf16 bf16x8 __attribute__((ext_vector_type(8)));
typedef float  f32x4  __attribute__((ext_vector_type(4)));

#define DIM   768
#define HEADS 12
#define HD    64
#define SEQ   4096
#define NKT   24   // 768 / BK32

// ---- async global->LDS, 16B per lane ----
__device__ __forceinline__ void gload16(const void* g, void* l) {
  typedef const __attribute__((address_space(1))) uint32_t* gp_t;
  typedef __attribute__((address_space(3))) uint32_t* lp_t;
  gp_t gp = reinterpret_cast<gp_t>(reinterpret_cast<uintptr_t>(g));
  lp_t lp = reinterpret_cast<lp_t>(reinterpret_cast<uintptr_t>(l));
  __builtin_amdgcn_global_load_lds(gp, lp, 16, 0, 0);
}

// ---- weight fp32 -> bf16 convert ----
__global__ __launch_bounds__(256) void wcvt_kernel(const float* __restrict__ src,
                                                   bf16* __restrict__ dst) {
  int i = (blockIdx.x * 256 + threadIdx.x) * 4;
  float4 v = *reinterpret_cast<const float4*>(src + i);
  bf16x4 o;
  o[0] = (bf16)v.x; o[1] = (bf16)v.y; o[2] = (bf16)v.z; o[3] = (bf16)v.w;
  *reinterpret_cast<bf16x4*>(dst + i) = o;
}

// ---- LayerNorm: one wave per row, fp32 stats, bf16 out ----
__global__ __launch_bounds__(256) void ln_kernel(const float* __restrict__ x,
    const float* __restrict__ gam, const float* __restrict__ bet,
    bf16* __restrict__ y) {
  const int tid = threadIdx.x, w = tid >> 6, l = tid & 63;
  const int row = blockIdx.x * 4 + w;
  const float* xr = x + (long)row * DIM;
  float4 v[3];
  float s = 0.f, ss = 0.f;
#pragma unroll
  for (int j = 0; j < 3; j++) {
    v[j] = *reinterpret_cast<const float4*>(xr + l * 4 + j * 256);
    s  += v[j].x + v[j].y + v[j].z + v[j].w;
    ss += v[j].x * v[j].x + v[j].y * v[j].y + v[j].z * v[j].z + v[j].w * v[j].w;
  }
#pragma unroll
  for (int m = 1; m < 64; m <<= 1) { s += __shfl_xor(s, m); ss += __shfl_xor(ss, m); }
  const float mu = s * (1.f / 768.f);
  const float rstd = rsqrtf(ss * (1.f / 768.f) - mu * mu + 1e-5f);
  bf16* yr = y + (long)row * DIM;
#pragma unroll
  for (int j = 0; j < 3; j++) {
    int c = l * 4 + j * 256;
    float4 g4 = *reinterpret_cast<const float4*>(gam + c);
    float4 b4 = *reinterpret_cast<const float4*>(bet + c);
    bf16x4 o;
    o[0] = (bf16)((v[j].x - mu) * rstd * g4.x + b4.x);
    o[1] = (bf16)((v[j].y - mu) * rstd * g4.y + b4.y);
    o[2] = (bf16)((v[j].z - mu) * rstd * g4.z + b4.z);
    o[3] = (bf16)((v[j].w - mu) * rstd * g4.w + b4.w);
    *reinterpret_cast<bf16x4*>(yr + c) = o;
  }
}

// ---- 128x128 bf16 MFMA GEMM, C = A[M,768] * Bw[N,768]^T ----
// Occupancy-first m97-class: 8 waves x (64x32) out -> acc[4][2]=32 regs/wave,
// single 16KB staging buffer, 2-barrier K-loop (compiler-managed waits),
// __launch_bounds__(512,4) -> 4 waves/SIMD (2 blocks/CU) for cross-block
// overlap (m114 mechanism). T1 bijective XCD swizzle + T2 XOR swizzle kept.
// MODE 0: qkv (elu+1 on q,k; scatter per-head), NT=18
// MODE 1: proj (+bias, fp32 out [t][768]), NT=6
template <int MODE>
__global__ __launch_bounds__(512, 4) void gemm_kernel(
    const bf16* __restrict__ A, const bf16* __restrict__ Bw,
    bf16* __restrict__ qb, bf16* __restrict__ kb, bf16* __restrict__ vb,
    float* __restrict__ outp, const float* __restrict__ bias) {
  // staging: [A 128x32 | B 128x32] bf16 = 16KB; epilogue reuses all 32KB as Cs
  __shared__ __align__(16) char lds[32768];
  const int tid = threadIdx.x;
  const int wid = tid >> 6, l = tid & 63;
  const int wr = wid >> 2, wc = wid & 3;      // 2 x 4 wave grid (64M x 32N each)
  const int l16 = l & 15, l4 = l >> 4;

  const int NT = (MODE == 0) ? 18 : 6;
  const int nwg = NT * 256;                    // M-tiles = 256
  const int orig = blockIdx.x;
  const int wgid = (orig & 7) * (nwg >> 3) + (orig >> 3);  // T1 bijective
  const int mt = wgid / NT, nt = wgid % NT;

  // staging source (1 A-chunk + 1 B-chunk per thread), inverse-swizzled col
  const int L = tid * 16;
  const int r = L >> 6;
  const int ce = ((L & 63) ^ (((L >> 7) & 3) << 4)) >> 1;
  const bf16* pA = A + (long)(mt * 128 + r) * DIM + ce;
  const bf16* pB = Bw + (long)(nt * 128 + r) * DIM + ce;

  // fragment LDS byte offsets (swizzled)
  int offA[4], offB[2];
#pragma unroll
  for (int mi = 0; mi < 4; mi++) {
    int off = (wr * 64 + mi * 16 + l16) * 64 + l4 * 16;
    offA[mi] = off ^ (((off >> 7) & 3) << 4);
  }
#pragma unroll
  for (int ni = 0; ni < 2; ni++) {
    int off = (wc * 32 + ni * 16 + l16) * 64 + l4 * 16;
    offB[ni] = 8192 + (off ^ (((off >> 7) & 3) << 4));
  }

  f32x4 acc[4][2];
#pragma unroll
  for (int m = 0; m < 4; m++)
#pragma unroll
    for (int n = 0; n < 2; n++) { f32x4 z4 = {0.f, 0.f, 0.f, 0.f}; acc[m][n] = z4; }

  for (int t = 0; t < NKT; t++) {
    __syncthreads();                       // everyone done reading tile t-1
    gload16(pA + t * 32, lds + L);
    gload16(pB + t * 32, lds + 8192 + L);
    __syncthreads();                       // (compiler drains vmcnt) tile t visible
    bf16x8 a[4], b[2];
#pragma unroll
    for (int mi = 0; mi < 4; mi++)
      a[mi] = *reinterpret_cast<const bf16x8*>(lds + offA[mi]);
#pragma unroll
    for (int ni = 0; ni < 2; ni++)
      b[ni] = *reinterpret_cast<const bf16x8*>(lds + offB[ni]);
#pragma unroll
    for (int mi = 0; mi < 4; mi++)
#pragma unroll
      for (int ni = 0; ni < 2; ni++)
        acc[mi][ni] = __builtin_amdgcn_mfma_f32_16x16x32_bf16(a[mi], b[ni], acc[mi][ni], 0, 0, 0);
  }

  if constexpr (MODE == 0) {
    // epilogue: Cs[128][128] bf16 (32KB, reuses staging LDS), coalesced scatter
    bf16* Cs = (bf16*)lds;
    const int s = nt / 6;   // 0=q, 1=k, 2=v (uniform per block)
    const int j = nt % 6;   // head pair
    bf16* dst0 = (s == 0) ? qb : (s == 1) ? kb : vb;
    __syncthreads();
#pragma unroll
    for (int mi = 0; mi < 4; mi++)
#pragma unroll
      for (int ni = 0; ni < 2; ni++)
#pragma unroll
        for (int i = 0; i < 4; i++) {
          float val = acc[mi][ni][i];
          if (s < 2) val = val > 0.f ? val + 1.f : __expf(val);
          Cs[(wr * 64 + mi * 16 + l4 * 4 + i) * 128 + wc * 32 + ni * 16 + l16] = (bf16)val;
        }
    __syncthreads();
#pragma unroll
    for (int it = 0; it < 4; it++) {
      int bi = it * 8192 + tid * 16;
      int row = bi >> 8;
      int col = (bi & 255) >> 1;
      int h = j * 2 + (col >> 6), d = col & 63;
      int trow = mt * 128 + row;
      int bb = trow >> 12, tok = trow & 4095;
      *reinterpret_cast<bf16x8*>(dst0 +
          ((long)(bb * HEADS + h) * SEQ + tok) * HD + d) =
          *reinterpret_cast<const bf16x8*>(Cs + (bi >> 1));
    }
  } else {
#pragma unroll
    for (int ni = 0; ni < 2; ni++) {
      int col = nt * 128 + wc * 32 + ni * 16 + l16;
      float bv = bias[col];
#pragma unroll
      for (int mi = 0; mi < 4; mi++)
#pragma unroll
        for (int i = 0; i < 4; i++) {
          long trow = mt * 128 + wr * 64 + mi * 16 + l4 * 4 + i;
          outp[trow * DIM + col] = acc[mi][ni][i] + bv;
        }
    }
  }
}

// ---- kv partials: per (head, split of 512 tokens): kv[64][64] += k^T v ; ksum ----
__global__ __launch_bounds__(256) void kv_kernel(
    const bf16* __restrict__ kb, const bf16* __restrict__ vb,
    float* __restrict__ kv_part, float* __restrict__ ks_part) {
  __shared__ __align__(16) union UU {
    struct { bf16 Ks[128 * 64]; bf16 Vs[128 * 64]; } s;
    float red[8192];
  } u;
  __shared__ float ksred[4][64];
  const int head = blockIdx.x, sp = blockIdx.y;
  const int tid = threadIdx.x, w = tid >> 6, l = tid & 63;
  const int d0 = (l >> 3) * 8, e0 = (l & 7) * 8;
  const bf16* K = kb + (long)(head * SEQ + sp * 512) * HD;
  const bf16* V = vb + (long)(head * SEQ + sp * 512) * HD;
  float acc[8][8];
#pragma unroll
  for (int i = 0; i < 8; i++)
#pragma unroll
    for (int jj = 0; jj < 8; jj++) acc[i][jj] = 0.f;
  float ks[8] = {0.f, 0.f, 0.f, 0.f, 0.f, 0.f, 0.f, 0.f};

  for (int t0 = 0; t0 < 512; t0 += 128) {
    __syncthreads();
#pragma unroll
    for (int r = 0; r < 4; r++) {
      gload16(K + t0 * 64 + r * 2048 + tid * 8, u.s.Ks + r * 2048 + tid * 8);
      gload16(V + t0 * 64 + r * 2048 + tid * 8, u.s.Vs + r * 2048 + tid * 8);
    }
    __syncthreads();
    for (int n = w * 32; n < w * 32 + 32; n++) {
      bf16x8 k8 = *reinterpret_cast<const bf16x8*>(u.s.Ks + n * 64 + d0);
      bf16x8 v8 = *reinterpret_cast<const bf16x8*>(u.s.Vs + n * 64 + e0);
      float kf[8], vf[8];
#pragma unroll
      for (int i = 0; i < 8; i++) { kf[i] = (float)k8[i]; vf[i] = (float)v8[i]; }
#pragma unroll
      for (int i = 0; i < 8; i++) {
        ks[i] += kf[i];
#pragma unroll
        for (int jj = 0; jj < 8; jj++) acc[i][jj] += kf[i] * vf[jj];
      }
    }
  }
  if ((l & 7) == 0) {
#pragma unroll
    for (int i = 0; i < 8; i++) ksred[w][d0 + i] = ks[i];
  }
  __syncthreads();
  if (w >= 2) {
    float* dst = u.red + (w - 2) * 4096;
#pragma unroll
    for (int i = 0; i < 8; i++) {
      f32x4 a = {acc[i][0], acc[i][1], acc[i][2], acc[i][3]};
      f32x4 b = {acc[i][4], acc[i][5], acc[i][6], acc[i][7]};
      *reinterpret_cast<f32x4*>(dst + (d0 + i) * 64 + e0) = a;
      *reinterpret_cast<f32x4*>(dst + (d0 + i) * 64 + e0 + 4) = b;
    }
  }
  __syncthreads();
  if (w < 2) {
    const float* src = u.red + w * 4096;
#pragma unroll
    for (int i = 0; i < 8; i++)
#pragma unroll
      for (int jj = 0; jj < 8; jj++) acc[i][jj] += src[(d0 + i) * 64 + e0 + jj];
  }
  __syncthreads();
  if (w == 1) {
    float* dst = u.red;
#pragma unroll
    for (int i = 0; i < 8; i++) {
      f32x4 a = {acc[i][0], acc[i][1], acc[i][2], acc[i][3]};
      f32x4 b = {acc[i][4], acc[i][5], acc[i][6], acc[i][7]};
      *reinterpret_cast<f32x4*>(dst + (d0 + i) * 64 + e0) = a;
      *reinterpret_cast<f32x4*>(dst + (d0 + i) * 64 + e0 + 4) = b;
    }
  }
  __syncthreads();
  if (w == 0) {
    const float* src = u.red;
#pragma unroll
    for (int i = 0; i < 8; i++)
#pragma unroll
      for (int jj = 0; jj < 8; jj++) acc[i][jj] += src[(d0 + i) * 64 + e0 + jj];
    float* dst = kv_part + (long)(head * 8 + sp) * 4096;
#pragma unroll
    for (int i = 0; i < 8; i++) {
      f32x4 a = {acc[i][0], acc[i][1], acc[i][2], acc[i][3]};
      f32x4 b = {acc[i][4], acc[i][5], acc[i][6], acc[i][7]};
      *reinterpret_cast<f32x4*>(dst + (d0 + i) * 64 + e0) = a;
      *reinterpret_cast<f32x4*>(dst + (d0 + i) * 64 + e0 + 4) = b;
    }
  }
  if (tid < 64)
    ks_part[(head * 8 + sp) * 64 + tid] =
        ksred[0][tid] + ksred[1][tid] + ksred[2][tid] + ksred[3][tid];
}

// ---- finalize: sum partials -> kvT bf16 [head][e][d], ksum fp32 [head][d] ----
__global__ __launch_bounds__(256) void kvfin_kernel(const float* __restrict__ kv_part,
    const float* __restrict__ ks_part, bf16* __restrict__ kvT, float* __restrict__ ksum) {
  const int head = blockIdx.x, tid = threadIdx.x;
  const long base = (long)head * 8 * 4096;
  const int d = tid >> 2, ecol = (tid & 3) * 16;
  float s[16];
#pragma unroll
  for (int q = 0; q < 16; q++) s[q] = 0.f;
  for (int sp = 0; sp < 8; sp++) {
    const float* p = kv_part + base + sp * 4096 + d * 64 + ecol;
#pragma unroll
    for (int q = 0; q < 16; q++) s[q] += p[q];
  }
#pragma unroll
  for (int q = 0; q < 16; q++) kvT[head * 4096 + (ecol + q) * 64 + d] = (bf16)s[q];
  if (tid < 64) {
    float t = 0.f;
    for (int sp = 0; sp < 8; sp++) t += ks_part[(head * 8 + sp) * 64 + tid];
    ksum[head * 64 + tid] = t;
  }
}

// ---- out_pre = (Q @ kv) * z, bf16 out in [t][768] layout ----
__global__ __launch_bounds__(256) void qout_kernel(const bf16* __restrict__ qb,
    const bf16* __restrict__ kvT, const float* __restrict__ ksum,
    bf16* __restrict__ outp) {
  __shared__ __align__(16) bf16 Qs[128 * 64];
  __shared__ __align__(16) bf16 Bs2[64 * 64];
  __shared__ float ksum_s[64];
  __shared__ float z_s[128];
  const int head = blockIdx.x, tt = blockIdx.y;
  const int b = head / HEADS, h = head % HEADS;
  const int tid = threadIdx.x, w = tid >> 6, l = tid & 63;
  const int l16 = l & 15, l4 = l >> 4;
  const bf16* Qg = qb + (long)(head * SEQ + tt * 128) * HD;
#pragma unroll
  for (int r = 0; r < 4; r++) gload16(Qg + r * 2048 + tid * 8, Qs + r * 2048 + tid * 8);
#pragma unroll
  for (int r = 0; r < 2; r++)
    gload16(kvT + head * 4096 + r * 2048 + tid * 8, Bs2 + r * 2048 + tid * 8);
  if (tid < 64) ksum_s[tid] = ksum[head * 64 + tid];
  __syncthreads();
  if (tid < 128) {
    float dsum = 0.f;
#pragma unroll
    for (int i = 0; i < 8; i++) {
      bf16x8 q8 = *reinterpret_cast<const bf16x8*>(Qg + tid * 64 + i * 8);
#pragma unroll
      for (int jj = 0; jj < 8; jj++) dsum += (float)q8[jj] * ksum_s[i * 8 + jj];
    }
    z_s[tid] = 1.f / (dsum + 1e-6f);
  }
  f32x4 acc[2][4];
#pragma unroll
  for (int m = 0; m < 2; m++)
#pragma unroll
    for (int n = 0; n < 4; n++) { f32x4 z4 = {0.f, 0.f, 0.f, 0.f}; acc[m][n] = z4; }
#pragma unroll
  for (int kk = 0; kk < 2; kk++) {
    bf16x8 af[2], bfr[4];
#pragma unroll
    for (int m = 0; m < 2; m++)
      af[m] = *reinterpret_cast<const bf16x8*>(Qs + (w * 32 + m * 16 + l16) * 64 + kk * 32 + l4 * 8);
#pragma unroll
    for (int n = 0; n < 4; n++)
      bfr[n] = *reinterpret_cast<const bf16x8*>(Bs2 + (n * 16 + l16) * 64 + kk * 32 + l4 * 8);
#pragma unroll
    for (int m = 0; m < 2; m++)
#pragma unroll
      for (int n = 0; n < 4; n++)
        acc[m][n] = __builtin_amdgcn_mfma_f32_16x16x32_bf16(af[m], bfr[n], acc[m][n], 0, 0, 0);
  }
  __syncthreads();
#pragma unroll
  for (int m = 0; m < 2; m++)
#pragma unroll
    for (int n = 0; n < 4; n++)
#pragma unroll
      for (int i = 0; i < 4; i++) {
        int row = w * 32 + m * 16 + l4 * 4 + i;
        Qs[row * 64 + n * 16 + l16] = (bf16)(acc[m][n][i] * z_s[row]);
      }
  __syncthreads();
#pragma unroll
  for (int r = 0; r < 4; r++) {
    int idx = r * 2048 + tid * 8;
    int row = idx >> 6, col = idx & 63;
    *reinterpret_cast<bf16x8*>(outp + (long)(b * SEQ + tt * 128 + row) * DIM + h * HD + col) =
        *reinterpret_cast<const bf16x8*>(Qs + idx);
  }
}

extern "C" void kernel_launch(void* const* d_in, const int* in_sizes, int n_in,
                              void* d_out, int out_size, void* d_ws, size_t ws_size,
                              hipStream_t stream) {
  const float* x     = (const float*)d_in[0];
  const float* gam   = (const float*)d_in[1];
  const float* bet   = (const float*)d_in[2];
  const float* wqkv  = (const float*)d_in[3];
  const float* wproj = (const float*)d_in[4];
  const float* bproj = (const float*)d_in[5];
  float* out = (float*)d_out;
  char* ws = (char*)d_ws;

  bf16*  y       = (bf16*)(ws);                    // 50331648 B (reused as out_pre)
  bf16*  qb      = (bf16*)(ws + 50331648);         // 50331648 B
  bf16*  kb      = (bf16*)(ws + 100663296);        // 50331648 B
  bf16*  vb      = (bf16*)(ws + 150994944);        // 50331648 B
  bf16*  wqkv_b  = (bf16*)(ws + 201326592);        // 3538944 B
  bf16*  wproj_b = (bf16*)(ws + 204865536);        // 1179648 B
  float* kv_part = (float*)(ws + 206045184);       // 12582912 B
  float* ks_part = (float*)(ws + 218628096);       // 196608 B
  bf16*  kvT     = (bf16*)(ws + 218824704);        // 786432 B
  float* ksum    = (float*)(ws + 219611136);       // 24576 B

  wcvt_kernel<<<1728, 256, 0, stream>>>(wqkv, wqkv_b);
  wcvt_kernel<<<576, 256, 0, stream>>>(wproj, wproj_b);
  ln_kernel<<<8192, 256, 0, stream>>>(x, gam, bet, y);
  gemm_kernel<0><<<dim3(18 * 256), 512, 0, stream>>>(y, wqkv_b, qb, kb, vb, nullptr, nullptr);
  kv_kernel<<<dim3(96, 8), 256, 0, stream>>>(kb, vb, kv_part, ks_part);
  kvfin_kernel<<<96, 256, 0, stream>>>(kv_part, ks_part, kvT, ksum);
  qout_kernel<<<dim3(96, 32), 256, 0, stream>>>(qb, kvT, ksum, y);
  gemm_kernel<1><<<dim3(6 * 256), 512, 0, stream>>>(y, wproj_b, nullptr, nullptr, nullptr, out, bproj);
}

// Round 8
// 292.978 us; speedup vs baseline: 1.3473x; 1.1049x over previous
//
#include <hip/hip_runtime.h>
#include <stdint.h>

typedef __bf16 bf16;
typedef __bf16 bf16x4 __attribute__((ext_vector_type(4)));
typedef __bf16 bf16x8 __attribute__((ext_vector_type(8)));
typedef float  f32x4  __attribute__((ext_vector_type(4)));

#define DIM   768
#define HEADS 12
#define HD    64
#define SEQ   4096
#define NKT2  12   // 768 / BK64

// ---- async global->LDS, 16B per lane ----
__device__ __forceinline__ void gload16(const void* g, void* l) {
  typedef const __attribute__((address_space(1))) uint32_t* gp_t;
  typedef __attribute__((address_space(3))) uint32_t* lp_t;
  gp_t gp = reinterpret_cast<gp_t>(reinterpret_cast<uintptr_t>(g));
  lp_t lp = reinterpret_cast<lp_t>(reinterpret_cast<uintptr_t>(l));
  __builtin_amdgcn_global_load_lds(gp, lp, 16, 0, 0);
}

// ---- weight fp32 -> bf16 convert ----
__global__ __launch_bounds__(256) void wcvt_kernel(const float* __restrict__ src,
                                                   bf16* __restrict__ dst) {
  int i = (blockIdx.x * 256 + threadIdx.x) * 4;
  float4 v = *reinterpret_cast<const float4*>(src + i);
  bf16x4 o;
  o[0] = (bf16)v.x; o[1] = (bf16)v.y; o[2] = (bf16)v.z; o[3] = (bf16)v.w;
  *reinterpret_cast<bf16x4*>(dst + i) = o;
}

// ---- LayerNorm: one wave per row, fp32 stats, bf16 out ----
__global__ __launch_bounds__(256) void ln_kernel(const float* __restrict__ x,
    const float* __restrict__ gam, const float* __restrict__ bet,
    bf16* __restrict__ y) {
  const int tid = threadIdx.x, w = tid >> 6, l = tid & 63;
  const int row = blockIdx.x * 4 + w;
  const float* xr = x + (long)row * DIM;
  float4 v[3];
  float s = 0.f, ss = 0.f;
#pragma unroll
  for (int j = 0; j < 3; j++) {
    v[j] = *reinterpret_cast<const float4*>(xr + l * 4 + j * 256);
    s  += v[j].x + v[j].y + v[j].z + v[j].w;
    ss += v[j].x * v[j].x + v[j].y * v[j].y + v[j].z * v[j].z + v[j].w * v[j].w;
  }
#pragma unroll
  for (int m = 1; m < 64; m <<= 1) { s += __shfl_xor(s, m); ss += __shfl_xor(ss, m); }
  const float mu = s * (1.f / 768.f);
  const float rstd = rsqrtf(ss * (1.f / 768.f) - mu * mu + 1e-5f);
  bf16* yr = y + (long)row * DIM;
#pragma unroll
  for (int j = 0; j < 3; j++) {
    int c = l * 4 + j * 256;
    float4 g4 = *reinterpret_cast<const float4*>(gam + c);
    float4 b4 = *reinterpret_cast<const float4*>(bet + c);
    bf16x4 o;
    o[0] = (bf16)((v[j].x - mu) * rstd * g4.x + b4.x);
    o[1] = (bf16)((v[j].y - mu) * rstd * g4.y + b4.y);
    o[2] = (bf16)((v[j].z - mu) * rstd * g4.z + b4.z);
    o[3] = (bf16)((v[j].w - mu) * rstd * g4.w + b4.w);
    *reinterpret_cast<bf16x4*>(yr + c) = o;
  }
}

// ---- 128x128 bf16 MFMA GEMM, C = A[M,768] * Bw[N,768]^T ----
// Round-7 occupancy-first structure + BK=64: 12 K-iters (half the barrier
// pairs), 16 MFMA/wave/iter, 32KB staging. 8 waves x (64x32) out,
// acc[4][2], __launch_bounds__(512,4). T1 + T2 (128B-row swizzle).
// MODE 0: qkv (elu+1 on q,k; scatter per-head), NT=18
// MODE 1: proj (+bias, fp32 out [t][768]), NT=6
template <int MODE>
__global__ __launch_bounds__(512, 4) void gemm_kernel(
    const bf16* __restrict__ A, const bf16* __restrict__ Bw,
    bf16* __restrict__ qb, bf16* __restrict__ kb, bf16* __restrict__ vb,
    float* __restrict__ outp, const float* __restrict__ bias) {
  // staging: [A 128x64 | B 128x64] bf16 = 32KB; epilogue reuses as Cs 32KB
  __shared__ __align__(16) char lds[32768];
  const int tid = threadIdx.x;
  const int wid = tid >> 6, l = tid & 63;
  const int wr = wid >> 2, wc = wid & 3;      // 2 x 4 wave grid (64M x 32N each)
  const int l16 = l & 15, l4 = l >> 4;

  const int NT = (MODE == 0) ? 18 : 6;
  const int nwg = NT * 256;                    // M-tiles = 256
  const int orig = blockIdx.x;
  const int wgid = (orig & 7) * (nwg >> 3) + (orig >> 3);  // T1 bijective
  const int mt = wgid / NT, nt = wgid % NT;

  // staging sources: rows are 128B (64 elems); slot = byte[6:4], swizzled by row&7.
  // Linear LDS dest (gload_lds requirement), inverse-swizzled global source.
  const int L0 = tid * 16, L1 = 8192 + tid * 16;
  const int r0 = L0 >> 7, s0 = (L0 >> 4) & 7;
  const int r1 = L1 >> 7, s1 = (L1 >> 4) & 7;
  const bf16* pA0 = A + (long)(mt * 128 + r0) * DIM + (s0 ^ (r0 & 7)) * 8;
  const bf16* pA1 = A + (long)(mt * 128 + r1) * DIM + (s1 ^ (r1 & 7)) * 8;
  const bf16* pB0 = Bw + (long)(nt * 128 + r0) * DIM + (s0 ^ (r0 & 7)) * 8;
  const bf16* pB1 = Bw + (long)(nt * 128 + r1) * DIM + (s1 ^ (r1 & 7)) * 8;

  // fragment LDS byte offsets (swizzled): row*128 + ((l4+4*ks)^(row&7))*16
  int offA[2][4], offB[2][2];
#pragma unroll
  for (int ks = 0; ks < 2; ks++) {
#pragma unroll
    for (int mi = 0; mi < 4; mi++) {
      int row = wr * 64 + mi * 16 + l16;
      offA[ks][mi] = row * 128 + (((l4 + 4 * ks) ^ (l16 & 7)) << 4);
    }
#pragma unroll
    for (int ni = 0; ni < 2; ni++) {
      int row = wc * 32 + ni * 16 + l16;
      offB[ks][ni] = 16384 + row * 128 + (((l4 + 4 * ks) ^ (l16 & 7)) << 4);
    }
  }

  f32x4 acc[4][2];
#pragma unroll
  for (int m = 0; m < 4; m++)
#pragma unroll
    for (int n = 0; n < 2; n++) { f32x4 z4 = {0.f, 0.f, 0.f, 0.f}; acc[m][n] = z4; }

  for (int t = 0; t < NKT2; t++) {
    __syncthreads();                       // everyone done reading tile t-1
    gload16(pA0 + t * 64, lds + L0);
    gload16(pA1 + t * 64, lds + L1);
    gload16(pB0 + t * 64, lds + 16384 + L0);
    gload16(pB1 + t * 64, lds + 16384 + L1);
    __syncthreads();                       // tile t visible (compiler drains)
#pragma unroll
    for (int ks = 0; ks < 2; ks++) {
      bf16x8 a[4], b[2];
#pragma unroll
      for (int mi = 0; mi < 4; mi++)
        a[mi] = *reinterpret_cast<const bf16x8*>(lds + offA[ks][mi]);
#pragma unroll
      for (int ni = 0; ni < 2; ni++)
        b[ni] = *reinterpret_cast<const bf16x8*>(lds + offB[ks][ni]);
#pragma unroll
      for (int mi = 0; mi < 4; mi++)
#pragma unroll
        for (int ni = 0; ni < 2; ni++)
          acc[mi][ni] = __builtin_amdgcn_mfma_f32_16x16x32_bf16(a[mi], b[ni], acc[mi][ni], 0, 0, 0);
    }
  }

  if constexpr (MODE == 0) {
    // epilogue: Cs[128][128] bf16 (32KB, reuses staging LDS), coalesced scatter
    bf16* Cs = (bf16*)lds;
    const int s = nt / 6;   // 0=q, 1=k, 2=v (uniform per block)
    const int j = nt % 6;   // head pair
    bf16* dst0 = (s == 0) ? qb : (s == 1) ? kb : vb;
    __syncthreads();
#pragma unroll
    for (int mi = 0; mi < 4; mi++)
#pragma unroll
      for (int ni = 0; ni < 2; ni++)
#pragma unroll
        for (int i = 0; i < 4; i++) {
          float val = acc[mi][ni][i];
          if (s < 2) val = val > 0.f ? val + 1.f : __expf(val);
          Cs[(wr * 64 + mi * 16 + l4 * 4 + i) * 128 + wc * 32 + ni * 16 + l16] = (bf16)val;
        }
    __syncthreads();
#pragma unroll
    for (int it = 0; it < 4; it++) {
      int bi = it * 8192 + tid * 16;
      int row = bi >> 8;
      int col = (bi & 255) >> 1;
      int h = j * 2 + (col >> 6), d = col & 63;
      int trow = mt * 128 + row;
      int bb = trow >> 12, tok = trow & 4095;
      *reinterpret_cast<bf16x8*>(dst0 +
          ((long)(bb * HEADS + h) * SEQ + tok) * HD + d) =
          *reinterpret_cast<const bf16x8*>(Cs + (bi >> 1));
    }
  } else {
#pragma unroll
    for (int ni = 0; ni < 2; ni++) {
      int col = nt * 128 + wc * 32 + ni * 16 + l16;
      float bv = bias[col];
#pragma unroll
      for (int mi = 0; mi < 4; mi++)
#pragma unroll
        for (int i = 0; i < 4; i++) {
          long trow = mt * 128 + wr * 64 + mi * 16 + l4 * 4 + i;
          outp[trow * DIM + col] = acc[mi][ni][i] + bv;
        }
    }
  }
}

// ---- kv partials: per (head, split of 512 tokens): kv[64][64] += k^T v ; ksum ----
__global__ __launch_bounds__(256) void kv_kernel(
    const bf16* __restrict__ kb, const bf16* __restrict__ vb,
    float* __restrict__ kv_part, float* __restrict__ ks_part) {
  __shared__ __align__(16) union UU {
    struct { bf16 Ks[128 * 64]; bf16 Vs[128 * 64]; } s;
    float red[8192];
  } u;
  __shared__ float ksred[4][64];
  const int head = blockIdx.x, sp = blockIdx.y;
  const int tid = threadIdx.x, w = tid >> 6, l = tid & 63;
  const int d0 = (l >> 3) * 8, e0 = (l & 7) * 8;
  const bf16* K = kb + (long)(head * SEQ + sp * 512) * HD;
  const bf16* V = vb + (long)(head * SEQ + sp * 512) * HD;
  float acc[8][8];
#pragma unroll
  for (int i = 0; i < 8; i++)
#pragma unroll
    for (int jj = 0; jj < 8; jj++) acc[i][jj] = 0.f;
  float ks[8] = {0.f, 0.f, 0.f, 0.f, 0.f, 0.f, 0.f, 0.f};

  for (int t0 = 0; t0 < 512; t0 += 128) {
    __syncthreads();
#pragma unroll
    for (int r = 0; r < 4; r++) {
      gload16(K + t0 * 64 + r * 2048 + tid * 8, u.s.Ks + r * 2048 + tid * 8);
      gload16(V + t0 * 64 + r * 2048 + tid * 8, u.s.Vs + r * 2048 + tid * 8);
    }
    __syncthreads();
    for (int n = w * 32; n < w * 32 + 32; n++) {
      bf16x8 k8 = *reinterpret_cast<const bf16x8*>(u.s.Ks + n * 64 + d0);
      bf16x8 v8 = *reinterpret_cast<const bf16x8*>(u.s.Vs + n * 64 + e0);
      float kf[8], vf[8];
#pragma unroll
      for (int i = 0; i < 8; i++) { kf[i] = (float)k8[i]; vf[i] = (float)v8[i]; }
#pragma unroll
      for (int i = 0; i < 8; i++) {
        ks[i] += kf[i];
#pragma unroll
        for (int jj = 0; jj < 8; jj++) acc[i][jj] += kf[i] * vf[jj];
      }
    }
  }
  if ((l & 7) == 0) {
#pragma unroll
    for (int i = 0; i < 8; i++) ksred[w][d0 + i] = ks[i];
  }
  __syncthreads();
  if (w >= 2) {
    float* dst = u.red + (w - 2) * 4096;
#pragma unroll
    for (int i = 0; i < 8; i++) {
      f32x4 a = {acc[i][0], acc[i][1], acc[i][2], acc[i][3]};
      f32x4 b = {acc[i][4], acc[i][5], acc[i][6], acc[i][7]};
      *reinterpret_cast<f32x4*>(dst + (d0 + i) * 64 + e0) = a;
      *reinterpret_cast<f32x4*>(dst + (d0 + i) * 64 + e0 + 4) = b;
    }
  }
  __syncthreads();
  if (w < 2) {
    const float* src = u.red + w * 4096;
#pragma unroll
    for (int i = 0; i < 8; i++)
#pragma unroll
      for (int jj = 0; jj < 8; jj++) acc[i][jj] += src[(d0 + i) * 64 + e0 + jj];
  }
  __syncthreads();
  if (w == 1) {
    float* dst = u.red;
#pragma unroll
    for (int i = 0; i < 8; i++) {
      f32x4 a = {acc[i][0], acc[i][1], acc[i][2], acc[i][3]};
      f32x4 b = {acc[i][4], acc[i][5], acc[i][6], acc[i][7]};
      *reinterpret_cast<f32x4*>(dst + (d0 + i) * 64 + e0) = a;
      *reinterpret_cast<f32x4*>(dst + (d0 + i) * 64 + e0 + 4) = b;
    }
  }
  __syncthreads();
  if (w == 0) {
    const float* src = u.red;
#pragma unroll
    for (int i = 0; i < 8; i++)
#pragma unroll
      for (int jj = 0; jj < 8; jj++) acc[i][jj] += src[(d0 + i) * 64 + e0 + jj];
    float* dst = kv_part + (long)(head * 8 + sp) * 4096;
#pragma unroll
    for (int i = 0; i < 8; i++) {
      f32x4 a = {acc[i][0], acc[i][1], acc[i][2], acc[i][3]};
      f32x4 b = {acc[i][4], acc[i][5], acc[i][6], acc[i][7]};
      *reinterpret_cast<f32x4*>(dst + (d0 + i) * 64 + e0) = a;
      *reinterpret_cast<f32x4*>(dst + (d0 + i) * 64 + e0 + 4) = b;
    }
  }
  if (tid < 64)
    ks_part[(head * 8 + sp) * 64 + tid] =
        ksred[0][tid] + ksred[1][tid] + ksred[2][tid] + ksred[3][tid];
}

// ---- finalize: sum partials -> kvT bf16 [head][e][d], ksum fp32 [head][d] ----
__global__ __launch_bounds__(256) void kvfin_kernel(const float* __restrict__ kv_part,
    const float* __restrict__ ks_part, bf16* __restrict__ kvT, float* __restrict__ ksum) {
  const int head = blockIdx.x, tid = threadIdx.x;
  const long base = (long)head * 8 * 4096;
  const int d = tid >> 2, ecol = (tid & 3) * 16;
  float s[16];
#pragma unroll
  for (int q = 0; q < 16; q++) s[q] = 0.f;
  for (int sp = 0; sp < 8; sp++) {
    const float* p = kv_part + base + sp * 4096 + d * 64 + ecol;
#pragma unroll
    for (int q = 0; q < 16; q++) s[q] += p[q];
  }
#pragma unroll
  for (int q = 0; q < 16; q++) kvT[head * 4096 + (ecol + q) * 64 + d] = (bf16)s[q];
  if (tid < 64) {
    float t = 0.f;
    for (int sp = 0; sp < 8; sp++) t += ks_part[(head * 8 + sp) * 64 + tid];
    ksum[head * 64 + tid] = t;
  }
}

// ---- out_pre = (Q @ kv) * z, bf16 out in [t][768] layout ----
__global__ __launch_bounds__(256) void qout_kernel(const bf16* __restrict__ qb,
    const bf16* __restrict__ kvT, const float* __restrict__ ksum,
    bf16* __restrict__ outp) {
  __shared__ __align__(16) bf16 Qs[128 * 64];
  __shared__ __align__(16) bf16 Bs2[64 * 64];
  __shared__ float ksum_s[64];
  __shared__ float z_s[128];
  const int head = blockIdx.x, tt = blockIdx.y;
  const int b = head / HEADS, h = head % HEADS;
  const int tid = threadIdx.x, w = tid >> 6, l = tid & 63;
  const int l16 = l & 15, l4 = l >> 4;
  const bf16* Qg = qb + (long)(head * SEQ + tt * 128) * HD;
#pragma unroll
  for (int r = 0; r < 4; r++) gload16(Qg + r * 2048 + tid * 8, Qs + r * 2048 + tid * 8);
#pragma unroll
  for (int r = 0; r < 2; r++)
    gload16(kvT + head * 4096 + r * 2048 + tid * 8, Bs2 + r * 2048 + tid * 8);
  if (tid < 64) ksum_s[tid] = ksum[head * 64 + tid];
  __syncthreads();
  if (tid < 128) {
    float dsum = 0.f;
#pragma unroll
    for (int i = 0; i < 8; i++) {
      bf16x8 q8 = *reinterpret_cast<const bf16x8*>(Qg + tid * 64 + i * 8);
#pragma unroll
      for (int jj = 0; jj < 8; jj++) dsum += (float)q8[jj] * ksum_s[i * 8 + jj];
    }
    z_s[tid] = 1.f / (dsum + 1e-6f);
  }
  f32x4 acc[2][4];
#pragma unroll
  for (int m = 0; m < 2; m++)
#pragma unroll
    for (int n = 0; n < 4; n++) { f32x4 z4 = {0.f, 0.f, 0.f, 0.f}; acc[m][n] = z4; }
#pragma unroll
  for (int kk = 0; kk < 2; kk++) {
    bf16x8 af[2], bfr[4];
#pragma unroll
    for (int m = 0; m < 2; m++)
      af[m] = *reinterpret_cast<const bf16x8*>(Qs + (w * 32 + m * 16 + l16) * 64 + kk * 32 + l4 * 8);
#pragma unroll
    for (int n = 0; n < 4; n++)
      bfr[n] = *reinterpret_cast<const bf16x8*>(Bs2 + (n * 16 + l16) * 64 + kk * 32 + l4 * 8);
#pragma unroll
    for (int m = 0; m < 2; m++)
#pragma unroll
      for (int n = 0; n < 4; n++)
        acc[m][n] = __builtin_amdgcn_mfma_f32_16x16x32_bf16(af[m], bfr[n], acc[m][n], 0, 0, 0);
  }
  __syncthreads();
#pragma unroll
  for (int m = 0; m < 2; m++)
#pragma unroll
    for (int n = 0; n < 4; n++)
#pragma unroll
      for (int i = 0; i < 4; i++) {
        int row = w * 32 + m * 16 + l4 * 4 + i;
        Qs[row * 64 + n * 16 + l16] = (bf16)(acc[m][n][i] * z_s[row]);
      }
  __syncthreads();
#pragma unroll
  for (int r = 0; r < 4; r++) {
    int idx = r * 2048 + tid * 8;
    int row = idx >> 6, col = idx & 63;
    *reinterpret_cast<bf16x8*>(outp + (long)(b * SEQ + tt * 128 + row) * DIM + h * HD + col) =
        *reinterpret_cast<const bf16x8*>(Qs + idx);
  }
}

extern "C" void kernel_launch(void* const* d_in, const int* in_sizes, int n_in,
                              void* d_out, int out_size, void* d_ws, size_t ws_size,
                              hipStream_t stream) {
  const float* x     = (const float*)d_in[0];
  const float* gam   = (const float*)d_in[1];
  const float* bet   = (const float*)d_in[2];
  const float* wqkv  = (const float*)d_in[3];
  const float* wproj = (const float*)d_in[4];
  const float* bproj = (const float*)d_in[5];
  float* out = (float*)d_out;
  char* ws = (char*)d_ws;

  bf16*  y       = (bf16*)(ws);                    // 50331648 B (reused as out_pre)
  bf16*  qb      = (bf16*)(ws + 50331648);         // 50331648 B
  bf16*  kb      = (bf16*)(ws + 100663296);        // 50331648 B
  bf16*  vb      = (bf16*)(ws + 150994944);        // 50331648 B
  bf16*  wqkv_b  = (bf16*)(ws + 201326592);        // 3538944 B
  bf16*  wproj_b = (bf16*)(ws + 204865536);        // 1179648 B
  float* kv_part = (float*)(ws + 206045184);       // 12582912 B
  float* ks_part = (float*)(ws + 218628096);       // 196608 B
  bf16*  kvT     = (bf16*)(ws + 218824704);        // 786432 B
  float* ksum    = (float*)(ws + 219611136);       // 24576 B

  wcvt_kernel<<<1728, 256, 0, stream>>>(wqkv, wqkv_b);
  wcvt_kernel<<<576, 256, 0, stream>>>(wproj, wproj_b);
  ln_kernel<<<8192, 256, 0, stream>>>(x, gam, bet, y);
  gemm_kernel<0><<<dim3(18 * 256), 512, 0, stream>>>(y, wqkv_b, qb, kb, vb, nullptr, nullptr);
  kv_kernel<<<dim3(96, 8), 256, 0, stream>>>(kb, vb, kv_part, ks_part);
  kvfin_kernel<<<96, 256, 0, stream>>>(kv_part, ks_part, kvT, ksum);
  qout_kernel<<<dim3(96, 32), 256, 0, stream>>>(qb, kvT, ksum, y);
  gemm_kernel<1><<<dim3(6 * 256), 512, 0, stream>>>(y, wproj_b, nullptr, nullptr, nullptr, out, bproj);
}

// Round 9
// 269.821 us; speedup vs baseline: 1.4629x; 1.0858x over previous
//
#include <hip/hip_runtime.h>
#include <stdint.h>

typedef __bf16 bf16;
typedef __bf16 bf16x4 __attribute__((ext_vector_type(4)));
typedef __bf16 bf16x8 __attribute__((ext_vector_type(8)));
typedef float  f32x4  __attribute__((ext_vector_type(4)));

#define DIM   768
#define HEADS 12
#define HD    64
#define SEQ   4096
#define NKT2  12   // 768 / BK64

// ---- async global->LDS, 16B per lane ----
__device__ __forceinline__ void gload16(const void* g, void* l) {
  typedef const __attribute__((address_space(1))) uint32_t* gp_t;
  typedef __attribute__((address_space(3))) uint32_t* lp_t;
  gp_t gp = reinterpret_cast<gp_t>(reinterpret_cast<uintptr_t>(g));
  lp_t lp = reinterpret_cast<lp_t>(reinterpret_cast<uintptr_t>(l));
  __builtin_amdgcn_global_load_lds(gp, lp, 16, 0, 0);
}

// ---- weight fp32 -> bf16 convert ----
__global__ __launch_bounds__(256) void wcvt_kernel(const float* __restrict__ src,
                                                   bf16* __restrict__ dst) {
  int i = (blockIdx.x * 256 + threadIdx.x) * 4;
  float4 v = *reinterpret_cast<const float4*>(src + i);
  bf16x4 o;
  o[0] = (bf16)v.x; o[1] = (bf16)v.y; o[2] = (bf16)v.z; o[3] = (bf16)v.w;
  *reinterpret_cast<bf16x4*>(dst + i) = o;
}

// ---- LayerNorm: one wave per row, fp32 stats, bf16 out ----
__global__ __launch_bounds__(256) void ln_kernel(const float* __restrict__ x,
    const float* __restrict__ gam, const float* __restrict__ bet,
    bf16* __restrict__ y) {
  const int tid = threadIdx.x, w = tid >> 6, l = tid & 63;
  const int row = blockIdx.x * 4 + w;
  const float* xr = x + (long)row * DIM;
  float4 v[3];
  float s = 0.f, ss = 0.f;
#pragma unroll
  for (int j = 0; j < 3; j++) {
    v[j] = *reinterpret_cast<const float4*>(xr + l * 4 + j * 256);
    s  += v[j].x + v[j].y + v[j].z + v[j].w;
    ss += v[j].x * v[j].x + v[j].y * v[j].y + v[j].z * v[j].z + v[j].w * v[j].w;
  }
#pragma unroll
  for (int m = 1; m < 64; m <<= 1) { s += __shfl_xor(s, m); ss += __shfl_xor(ss, m); }
  const float mu = s * (1.f / 768.f);
  const float rstd = rsqrtf(ss * (1.f / 768.f) - mu * mu + 1e-5f);
  bf16* yr = y + (long)row * DIM;
#pragma unroll
  for (int j = 0; j < 3; j++) {
    int c = l * 4 + j * 256;
    float4 g4 = *reinterpret_cast<const float4*>(gam + c);
    float4 b4 = *reinterpret_cast<const float4*>(bet + c);
    bf16x4 o;
    o[0] = (bf16)((v[j].x - mu) * rstd * g4.x + b4.x);
    o[1] = (bf16)((v[j].y - mu) * rstd * g4.y + b4.y);
    o[2] = (bf16)((v[j].z - mu) * rstd * g4.z + b4.z);
    o[3] = (bf16)((v[j].w - mu) * rstd * g4.w + b4.w);
    *reinterpret_cast<bf16x4*>(yr + c) = o;
  }
}

// ---- 128x128 bf16 MFMA GEMM, C = A[M,768] * Bw[N,768]^T ----
// Round-8 structure (BK=64, occupancy-first). MODE 0 epilogue now writes
// q as [bh][n][d] but k,v TRANSPOSED as [bh][d][n] (for the MFMA kv kernel),
// via XOR-swizzled LDS transpose.
// MODE 0: qkv (elu+1 on q,k), NT=18 ; MODE 1: proj (+bias, fp32), NT=6
template <int MODE>
__global__ __launch_bounds__(512, 4) void gemm_kernel(
    const bf16* __restrict__ A, const bf16* __restrict__ Bw,
    bf16* __restrict__ qb, bf16* __restrict__ kb, bf16* __restrict__ vb,
    float* __restrict__ outp, const float* __restrict__ bias) {
  // staging: [A 128x64 | B 128x64] bf16 = 32KB; epilogue reuses as Cs 32KB
  __shared__ __align__(16) char lds[32768];
  const int tid = threadIdx.x;
  const int wid = tid >> 6, l = tid & 63;
  const int wr = wid >> 2, wc = wid & 3;      // 2 x 4 wave grid (64M x 32N each)
  const int l16 = l & 15, l4 = l >> 4;

  const int NT = (MODE == 0) ? 18 : 6;
  const int nwg = NT * 256;                    // M-tiles = 256
  const int orig = blockIdx.x;
  const int wgid = (orig & 7) * (nwg >> 3) + (orig >> 3);  // T1 bijective
  const int mt = wgid / NT, nt = wgid % NT;

  // staging sources: rows are 128B; slot = byte[6:4], swizzled by row&7.
  const int L0 = tid * 16, L1 = 8192 + tid * 16;
  const int r0 = L0 >> 7, s0 = (L0 >> 4) & 7;
  const int r1 = L1 >> 7, s1 = (L1 >> 4) & 7;
  const bf16* pA0 = A + (long)(mt * 128 + r0) * DIM + (s0 ^ (r0 & 7)) * 8;
  const bf16* pA1 = A + (long)(mt * 128 + r1) * DIM + (s1 ^ (r1 & 7)) * 8;
  const bf16* pB0 = Bw + (long)(nt * 128 + r0) * DIM + (s0 ^ (r0 & 7)) * 8;
  const bf16* pB1 = Bw + (long)(nt * 128 + r1) * DIM + (s1 ^ (r1 & 7)) * 8;

  // fragment LDS byte offsets (swizzled)
  int offA[2][4], offB[2][2];
#pragma unroll
  for (int ks = 0; ks < 2; ks++) {
#pragma unroll
    for (int mi = 0; mi < 4; mi++) {
      int row = wr * 64 + mi * 16 + l16;
      offA[ks][mi] = row * 128 + (((l4 + 4 * ks) ^ (l16 & 7)) << 4);
    }
#pragma unroll
    for (int ni = 0; ni < 2; ni++) {
      int row = wc * 32 + ni * 16 + l16;
      offB[ks][ni] = 16384 + row * 128 + (((l4 + 4 * ks) ^ (l16 & 7)) << 4);
    }
  }

  f32x4 acc[4][2];
#pragma unroll
  for (int m = 0; m < 4; m++)
#pragma unroll
    for (int n = 0; n < 2; n++) { f32x4 z4 = {0.f, 0.f, 0.f, 0.f}; acc[m][n] = z4; }

  for (int t = 0; t < NKT2; t++) {
    __syncthreads();
    gload16(pA0 + t * 64, lds + L0);
    gload16(pA1 + t * 64, lds + L1);
    gload16(pB0 + t * 64, lds + 16384 + L0);
    gload16(pB1 + t * 64, lds + 16384 + L1);
    __syncthreads();
#pragma unroll
    for (int ks = 0; ks < 2; ks++) {
      bf16x8 a[4], b[2];
#pragma unroll
      for (int mi = 0; mi < 4; mi++)
        a[mi] = *reinterpret_cast<const bf16x8*>(lds + offA[ks][mi]);
#pragma unroll
      for (int ni = 0; ni < 2; ni++)
        b[ni] = *reinterpret_cast<const bf16x8*>(lds + offB[ks][ni]);
#pragma unroll
      for (int mi = 0; mi < 4; mi++)
#pragma unroll
        for (int ni = 0; ni < 2; ni++)
          acc[mi][ni] = __builtin_amdgcn_mfma_f32_16x16x32_bf16(a[mi], b[ni], acc[mi][ni], 0, 0, 0);
    }
  }

  if constexpr (MODE == 0) {
    const int s = nt / 6;   // 0=q, 1=k, 2=v (uniform per block)
    const int j = nt % 6;   // head pair
    if (s == 0) {
      // q: linear [bh][n][d] scatter (round-8 path), elu+1
      bf16* Cs = (bf16*)lds;
      __syncthreads();
#pragma unroll
      for (int mi = 0; mi < 4; mi++)
#pragma unroll
        for (int ni = 0; ni < 2; ni++)
#pragma unroll
          for (int i = 0; i < 4; i++) {
            float val = acc[mi][ni][i];
            val = val > 0.f ? val + 1.f : __expf(val);
            Cs[(wr * 64 + mi * 16 + l4 * 4 + i) * 128 + wc * 32 + ni * 16 + l16] = (bf16)val;
          }
      __syncthreads();
#pragma unroll
      for (int it = 0; it < 4; it++) {
        int bi = it * 8192 + tid * 16;
        int row = bi >> 8;
        int col = (bi & 255) >> 1;
        int h = j * 2 + (col >> 6), d = col & 63;
        int trow = mt * 128 + row;
        int bb = trow >> 12, tok = trow & 4095;
        *reinterpret_cast<bf16x8*>(qb +
            ((long)(bb * HEADS + h) * SEQ + tok) * HD + d) =
            *reinterpret_cast<const bf16x8*>(Cs + (bi >> 1));
      }
    } else {
      // k (elu+1) / v: TRANSPOSED write to [bh][d][n] via swizzled Cs.
      // Cs element (tok, c) lives at byte tok*256 + ((c*2) ^ ((tok&7)<<4)).
      bf16* dst0 = (s == 1) ? kb : vb;
      __syncthreads();
#pragma unroll
      for (int mi = 0; mi < 4; mi++)
#pragma unroll
        for (int ni = 0; ni < 2; ni++)
#pragma unroll
          for (int i = 0; i < 4; i++) {
            float val = acc[mi][ni][i];
            if (s == 1) val = val > 0.f ? val + 1.f : __expf(val);
            int tr = wr * 64 + mi * 16 + l4 * 4 + i;
            int cc = wc * 32 + ni * 16 + l16;
            *reinterpret_cast<bf16*>(lds + tr * 256 + ((cc * 2) ^ ((tr & 7) << 4))) = (bf16)val;
          }
      __syncthreads();
      const int cc = tid & 127;         // column (head-dim index pair)
      const int sp2 = tid >> 7;         // token span 0..3 (32 toks each)
      const int hh = j * 2 + (cc >> 6), dd = cc & 63;
      const int bb = (mt * 128) >> 12;
      const int n0 = ((mt * 128) & 4095) + sp2 * 32;
      bf16* dstp = dst0 + ((long)(bb * HEADS + hh) * HD + dd) * SEQ + n0;
#pragma unroll
      for (int q8i = 0; q8i < 4; q8i++) {
        bf16x8 o;
#pragma unroll
        for (int jj = 0; jj < 8; jj++) {
          int tok = sp2 * 32 + q8i * 8 + jj;
          o[jj] = *reinterpret_cast<const bf16*>(lds + tok * 256 + ((cc * 2) ^ ((tok & 7) << 4)));
        }
        *reinterpret_cast<bf16x8*>(dstp + q8i * 8) = o;
      }
    }
  } else {
#pragma unroll
    for (int ni = 0; ni < 2; ni++) {
      int col = nt * 128 + wc * 32 + ni * 16 + l16;
      float bv = bias[col];
#pragma unroll
      for (int mi = 0; mi < 4; mi++)
#pragma unroll
        for (int i = 0; i < 4; i++) {
          long trow = mt * 128 + wr * 64 + mi * 16 + l4 * 4 + i;
          outp[trow * DIM + col] = acc[mi][ni][i] + bv;
        }
    }
  }
}

// ---- kv partials via MFMA: per (head, sp): kv[64][64] += KT·VT^T over 512 toks
// inputs: ktb, vtb in [bh][64][4096] (transposed). Also ksum partials.
__global__ __launch_bounds__(256) void kv_kernel(
    const bf16* __restrict__ ktb, const bf16* __restrict__ vtb,
    float* __restrict__ kv_part, float* __restrict__ ks_part) {
  // LDS: KT chunk [64 d][128 n] @0 (16KB), VT chunk [64 e][128 n] @16384.
  // rows 256B, element (r, cb) at byte r*256 + (cb ^ ((r&7)<<4)).
  __shared__ __align__(16) char lds[32768];
  const int head = blockIdx.x, sp = blockIdx.y;
  const int tid = threadIdx.x;
  const int wid = tid >> 6, l = tid & 63;
  const int wd = wid >> 1, we = wid & 1;       // 2x2 wave grid: 32d x 32e per wave
  const int l16 = l & 15, l4 = l >> 4;

  int offK[4][2], offV[4][2];
#pragma unroll
  for (int ks = 0; ks < 4; ks++) {
#pragma unroll
    for (int mi = 0; mi < 2; mi++) {
      int row = wd * 32 + mi * 16 + l16;
      offK[ks][mi] = row * 256 + ((ks * 64 + l4 * 16) ^ ((row & 7) << 4));
    }
#pragma unroll
    for (int ni = 0; ni < 2; ni++) {
      int row = we * 32 + ni * 16 + l16;
      offV[ks][ni] = 16384 + row * 256 + ((ks * 64 + l4 * 16) ^ ((row & 7) << 4));
    }
  }
  const bf16* srcK[4]; const bf16* srcV[4]; int ldst[4];
#pragma unroll
  for (int g = 0; g < 4; g++) {
    int L = g * 4096 + tid * 16;
    int r = L >> 8, cb = L & 255;
    int ce = (cb ^ ((r & 7) << 4)) >> 1;
    srcK[g] = ktb + ((long)head * HD + r) * SEQ + sp * 512 + ce;
    srcV[g] = vtb + ((long)head * HD + r) * SEQ + sp * 512 + ce;
    ldst[g] = L;
  }

  f32x4 acc[2][2];
#pragma unroll
  for (int m = 0; m < 2; m++)
#pragma unroll
    for (int n = 0; n < 2; n++) { f32x4 z4 = {0.f, 0.f, 0.f, 0.f}; acc[m][n] = z4; }
  float ksf = 0.f;
  const int ksd = tid >> 2, ksq = tid & 3;

  for (int c = 0; c < 4; c++) {          // 4 chunks of 128 tokens
    __syncthreads();
#pragma unroll
    for (int g = 0; g < 4; g++) {
      gload16(srcK[g] + c * 128, lds + ldst[g]);
      gload16(srcV[g] + c * 128, lds + 16384 + ldst[g]);
    }
    __syncthreads();
    // ksum partial from staged KT (d = tid>>2, quarter of 128 tokens)
#pragma unroll
    for (int q = 0; q < 4; q++) {
      bf16x8 k8 = *reinterpret_cast<const bf16x8*>(
          lds + ksd * 256 + ((ksq * 64 + q * 16) ^ ((ksd & 7) << 4)));
#pragma unroll
      for (int jj = 0; jj < 8; jj++) ksf += (float)k8[jj];
    }
#pragma unroll
    for (int ks = 0; ks < 4; ks++) {
      bf16x8 a[2], b[2];
      a[0] = *reinterpret_cast<const bf16x8*>(lds + offK[ks][0]);
      a[1] = *reinterpret_cast<const bf16x8*>(lds + offK[ks][1]);
      b[0] = *reinterpret_cast<const bf16x8*>(lds + offV[ks][0]);
      b[1] = *reinterpret_cast<const bf16x8*>(lds + offV[ks][1]);
#pragma unroll
      for (int mi = 0; mi < 2; mi++)
#pragma unroll
        for (int ni = 0; ni < 2; ni++)
          acc[mi][ni] = __builtin_amdgcn_mfma_f32_16x16x32_bf16(a[mi], b[ni], acc[mi][ni], 0, 0, 0);
    }
  }
  ksf += __shfl_xor(ksf, 1);
  ksf += __shfl_xor(ksf, 2);
  if (ksq == 0) ks_part[(head * 8 + sp) * 64 + ksd] = ksf;

  // kv tile out: stage f32 [64 d][64 e] in swizzled LDS, then coalesced write
  __syncthreads();
#pragma unroll
  for (int mi = 0; mi < 2; mi++)
#pragma unroll
    for (int ni = 0; ni < 2; ni++)
#pragma unroll
      for (int i = 0; i < 4; i++) {
        int dd = wd * 32 + mi * 16 + l4 * 4 + i;
        int ee = we * 32 + ni * 16 + l16;
        *reinterpret_cast<float*>(lds + dd * 256 + ((ee * 4) ^ ((dd & 7) << 4))) = acc[mi][ni][i];
      }
  __syncthreads();
  float* dst = kv_part + (long)(head * 8 + sp) * 4096;
  const int dd2 = tid >> 2, eq = tid & 3;
#pragma unroll
  for (int q = 0; q < 4; q++) {
    f32x4 v4 = *reinterpret_cast<const f32x4*>(
        lds + dd2 * 256 + ((eq * 64 + q * 16) ^ ((dd2 & 7) << 4)));
    *reinterpret_cast<f32x4*>(dst + dd2 * 64 + eq * 16 + q * 4) = v4;
  }
}

// ---- finalize: sum partials -> kvT bf16 [head][e][d], ksum fp32 [head][d] ----
__global__ __launch_bounds__(256) void kvfin_kernel(const float* __restrict__ kv_part,
    const float* __restrict__ ks_part, bf16* __restrict__ kvT, float* __restrict__ ksum) {
  const int head = blockIdx.x, tid = threadIdx.x;
  const long base = (long)head * 8 * 4096;
  const int d = tid >> 2, ecol = (tid & 3) * 16;
  float s[16];
#pragma unroll
  for (int q = 0; q < 16; q++) s[q] = 0.f;
  for (int sp = 0; sp < 8; sp++) {
    const float* p = kv_part + base + sp * 4096 + d * 64 + ecol;
#pragma unroll
    for (int q = 0; q < 16; q++) s[q] += p[q];
  }
#pragma unroll
  for (int q = 0; q < 16; q++) kvT[head * 4096 + (ecol + q) * 64 + d] = (bf16)s[q];
  if (tid < 64) {
    float t = 0.f;
    for (int sp = 0; sp < 8; sp++) t += ks_part[(head * 8 + sp) * 64 + tid];
    ksum[head * 64 + tid] = t;
  }
}

// ---- out_pre = (Q @ kv) * z, bf16 out in [t][768] layout ----
__global__ __launch_bounds__(256) void qout_kernel(const bf16* __restrict__ qb,
    const bf16* __restrict__ kvT, const float* __restrict__ ksum,
    bf16* __restrict__ outp) {
  __shared__ __align__(16) bf16 Qs[128 * 64];
  __shared__ __align__(16) bf16 Bs2[64 * 64];
  __shared__ float ksum_s[64];
  __shared__ float z_s[128];
  const int head = blockIdx.x, tt = blockIdx.y;
  const int b = head / HEADS, h = head % HEADS;
  const int tid = threadIdx.x, w = tid >> 6, l = tid & 63;
  const int l16 = l & 15, l4 = l >> 4;
  const bf16* Qg = qb + (long)(head * SEQ + tt * 128) * HD;
#pragma unroll
  for (int r = 0; r < 4; r++) gload16(Qg + r * 2048 + tid * 8, Qs + r * 2048 + tid * 8);
#pragma unroll
  for (int r = 0; r < 2; r++)
    gload16(kvT + head * 4096 + r * 2048 + tid * 8, Bs2 + r * 2048 + tid * 8);
  if (tid < 64) ksum_s[tid] = ksum[head * 64 + tid];
  __syncthreads();
  {
    // z from staged Qs (no global q re-read): 2 threads per token
    const int tok = tid >> 1, hf = tid & 1;
    float dsum = 0.f;
#pragma unroll
    for (int q = 0; q < 4; q++) {
      bf16x8 q8 = *reinterpret_cast<const bf16x8*>(Qs + tok * 64 + hf * 32 + q * 8);
#pragma unroll
      for (int jj = 0; jj < 8; jj++) dsum += (float)q8[jj] * ksum_s[hf * 32 + q * 8 + jj];
    }
    dsum += __shfl_xor(dsum, 1);
    if (hf == 0) z_s[tok] = 1.f / (dsum + 1e-6f);
  }
  f32x4 acc[2][4];
#pragma unroll
  for (int m = 0; m < 2; m++)
#pragma unroll
    for (int n = 0; n < 4; n++) { f32x4 z4 = {0.f, 0.f, 0.f, 0.f}; acc[m][n] = z4; }
#pragma unroll
  for (int kk = 0; kk < 2; kk++) {
    bf16x8 af[2], bfr[4];
#pragma unroll
    for (int m = 0; m < 2; m++)
      af[m] = *reinterpret_cast<const bf16x8*>(Qs + (w * 32 + m * 16 + l16) * 64 + kk * 32 + l4 * 8);
#pragma unroll
    for (int n = 0; n < 4; n++)
      bfr[n] = *reinterpret_cast<const bf16x8*>(Bs2 + (n * 16 + l16) * 64 + kk * 32 + l4 * 8);
#pragma unroll
    for (int m = 0; m < 2; m++)
#pragma unroll
      for (int n = 0; n < 4; n++)
        acc[m][n] = __builtin_amdgcn_mfma_f32_16x16x32_bf16(af[m], bfr[n], acc[m][n], 0, 0, 0);
  }
  __syncthreads();
#pragma unroll
  for (int m = 0; m < 2; m++)
#pragma unroll
    for (int n = 0; n < 4; n++)
#pragma unroll
      for (int i = 0; i < 4; i++) {
        int row = w * 32 + m * 16 + l4 * 4 + i;
        Qs[row * 64 + n * 16 + l16] = (bf16)(acc[m][n][i] * z_s[row]);
      }
  __syncthreads();
#pragma unroll
  for (int r = 0; r < 4; r++) {
    int idx = r * 2048 + tid * 8;
    int row = idx >> 6, col = idx & 63;
    *reinterpret_cast<bf16x8*>(outp + (long)(b * SEQ + tt * 128 + row) * DIM + h * HD + col) =
        *reinterpret_cast<const bf16x8*>(Qs + idx);
  }
}

extern "C" void kernel_launch(void* const* d_in, const int* in_sizes, int n_in,
                              void* d_out, int out_size, void* d_ws, size_t ws_size,
                              hipStream_t stream) {
  const float* x     = (const float*)d_in[0];
  const float* gam   = (const float*)d_in[1];
  const float* bet   = (const float*)d_in[2];
  const float* wqkv  = (const float*)d_in[3];
  const float* wproj = (const float*)d_in[4];
  const float* bproj = (const float*)d_in[5];
  float* out = (float*)d_out;
  char* ws = (char*)d_ws;

  bf16*  y       = (bf16*)(ws);                    // 50331648 B (reused as out_pre)
  bf16*  qb      = (bf16*)(ws + 50331648);         // 50331648 B  [bh][n][d]
  bf16*  kb      = (bf16*)(ws + 100663296);        // 50331648 B  [bh][d][n] (kT)
  bf16*  vb      = (bf16*)(ws + 150994944);        // 50331648 B  [bh][d][n] (vT)
  bf16*  wqkv_b  = (bf16*)(ws + 201326592);        // 3538944 B
  bf16*  wproj_b = (bf16*)(ws + 204865536);        // 1179648 B
  float* kv_part = (float*)(ws + 206045184);       // 12582912 B
  float* ks_part = (float*)(ws + 218628096);       // 196608 B
  bf16*  kvT     = (bf16*)(ws + 218824704);        // 786432 B
  float* ksum    = (float*)(ws + 219611136);       // 24576 B

  wcvt_kernel<<<1728, 256, 0, stream>>>(wqkv, wqkv_b);
  wcvt_kernel<<<576, 256, 0, stream>>>(wproj, wproj_b);
  ln_kernel<<<8192, 256, 0, stream>>>(x, gam, bet, y);
  gemm_kernel<0><<<dim3(18 * 256), 512, 0, stream>>>(y, wqkv_b, qb, kb, vb, nullptr, nullptr);
  kv_kernel<<<dim3(96, 8), 256, 0, stream>>>(kb, vb, kv_part, ks_part);
  kvfin_kernel<<<96, 256, 0, stream>>>(kv_part, ks_part, kvT, ksum);
  qout_kernel<<<dim3(96, 32), 256, 0, stream>>>(qb, kvT, ksum, y);
  gemm_kernel<1><<<dim3(6 * 256), 512, 0, stream>>>(y, wproj_b, nullptr, nullptr, nullptr, out, bproj);
}